// Round 8
// baseline (562.626 us; speedup 1.0000x reference)
//
#include <hip/hip_runtime.h>
#include <hip/hip_bf16.h>
#include <stdint.h>

#define DEV __device__ __forceinline__
#define WAITV(n) asm volatile("s_waitcnt vmcnt(" #n ")" ::: "memory")
#define WAITL(n) asm volatile("s_waitcnt lgkmcnt(" #n ")" ::: "memory")
#define SCHEDB __builtin_amdgcn_sched_barrier(0)

typedef __attribute__((ext_vector_type(4))) float f32x4;
typedef __attribute__((ext_vector_type(8))) short bf16x8;
typedef unsigned short u16;

constexpr int Bb = 4, Tt = 2048, Ccn = 2048, NHn = 16, HDn = 128;
constexpr int MM = Bb * Tt;          // 8192
constexpr int NQKV = 3 * Ccn;        // 6144
constexpr int KD = 2048;             // K dim for BOTH GEMMs
constexpr size_t K2 = (size_t)KD * 2;  // row stride bytes
constexpr float QSCALE = 0.08838834764831845f;  // 1/sqrt(128)

DEV u16 f2bf(float f) {
  __hip_bfloat16 h = __float2bfloat16(f);
  return *reinterpret_cast<u16*>(&h);
}

DEV void gl_lds16(const void* g, void* l) {
  __builtin_amdgcn_global_load_lds(
      (const __attribute__((address_space(1))) void*)g,
      (__attribute__((address_space(3))) void*)l, 16, 0, 0);
}

// ---------------- prep kernels ----------------

__global__ void k_rope_table(float* __restrict__ ct, float* __restrict__ st) {
  int idx = blockIdx.x * blockDim.x + threadIdx.x;
  if (idx >= Tt * 64) return;
  int t = idx >> 6, j = idx & 63;
  float invf = expf(-(float)j * 0.14391157f);  // ln(10000)/64
  float a = (float)t * invf;
  ct[idx] = cosf(a);
  st[idx] = sinf(a);
}

__global__ void k_cvt(const float* __restrict__ in, u16* __restrict__ out, int n) {
  int i = blockIdx.x * blockDim.x + threadIdx.x;
  int stride = gridDim.x * blockDim.x;
  int n4 = n >> 2;
  for (int idx = i; idx < n4; idx += stride) {
    float4 v = ((const float4*)in)[idx];
    ushort4 o;
    o.x = f2bf(v.x); o.y = f2bf(v.y); o.z = f2bf(v.z); o.w = f2bf(v.w);
    ((ushort4*)out)[idx] = o;
  }
}

// in: fp32 [R][NC]  ->  out: bf16 [NC][R]
__global__ void k_transpose_cvt(const float* __restrict__ in, u16* __restrict__ out,
                                int R, int NC) {
  __shared__ u16 tile[64][72];
  int tr = blockIdx.y * 64, tc = blockIdx.x * 64;
  int r = threadIdx.x >> 2, c = (threadIdx.x & 3) * 16;
  const float* src = in + (size_t)(tr + r) * NC + tc + c;
#pragma unroll
  for (int i = 0; i < 16; i++) tile[r][c + i] = f2bf(src[i]);
  __syncthreads();
  u16* dst = out + (size_t)(tc + r) * R + tr + c;
#pragma unroll
  for (int i = 0; i < 16; i++) dst[i] = tile[c + i][r];
}

// v [BH][T][D] -> vt [BH][D][T]
__global__ void k_vtrans(const u16* __restrict__ v, u16* __restrict__ vt) {
  __shared__ u16 tile[64][72];
  int bh = blockIdx.z;
  int t0 = blockIdx.x * 64, d0 = blockIdx.y * 64;
  int r = threadIdx.x >> 2, c = (threadIdx.x & 3) * 16;
  const u16* src = v + ((size_t)bh * Tt + t0) * HDn + d0;
#pragma unroll
  for (int i = 0; i < 16; i++) tile[r][c + i] = src[(size_t)r * HDn + c + i];
  __syncthreads();
  u16* dst = vt + ((size_t)bh * HDn + d0) * Tt + t0;
#pragma unroll
  for (int i = 0; i < 16; i++) dst[(size_t)r * Tt + c + i] = tile[c + i][r];
}

// ---------------- 256x256 8-phase GEMM, register-pipelined ---------------
// R7 diagnosis: ds_reads serialized with MFMA (reads(p) drained by lgkm(0)
// before MFMA(p)) -> LDS-array time + MFMA add up; 35% MfmaUtil wall.
// New: MFMA(p) consumes frags loaded at phase p-1. Each phase: barrier;
// issue NEXT phase's A-reads (+ next buf's B at gp3/gp7); issue stage;
// counted WAITV at gp2/gp6; counted lgkm (retire prev phase's reads ONLY,
// leave this phase's in flight under the MFMA); 16 MFMA. ONE barrier/phase.
// Hazards re-verified: every region restaged >=1 barrier + lgkm-retirement
// after its last read. Last iteration peeled for exact wait immediates.

template <int MODE>
__global__ __launch_bounds__(512, 2) void k_gemm256(
    const u16* __restrict__ A, const u16* __restrict__ Bt,
    int Ndim, int NBX,
    const float* __restrict__ bias,
    u16* __restrict__ q_r, u16* __restrict__ k_r, u16* __restrict__ v_r,
    const float* __restrict__ ctab, const float* __restrict__ stab,
    float* __restrict__ outp) {
  __shared__ __align__(16) u16 SM[65536];   // 128KB: A 64KB | B 64KB
  const int tid = threadIdx.x;
  const int w = tid >> 6, lane = tid & 63;
  const int l16 = lane & 15, l4 = lane >> 4;
  const int wr = w >> 2, wc = w & 3;
  const int bid = blockIdx.x, nwg = gridDim.x;
  const int swz = (bid & 7) * (nwg >> 3) + (bid >> 3);   // XCD-aware
  const int by = swz / NBX, bx = swz % NBX;
  const int m0 = by * 256, n0 = bx * 256;
  constexpr int NT = KD >> 6;      // 32
  constexpr int NIT = NT >> 1;     // 16

  // ---- precomputed LDS read bases (lane-constant, R7 algebraic split) ----
  const int Mx = (l16 & 7) << 4;
  const int b6 = Mx & 64;
  const int lane_lo = l16 * 128 + ((l4 * 16) ^ (Mx & 48));
  const char* const pA0 = (const char*)SM + wr * 16384 + lane_lo + b6;
  const char* const pA1 = (const char*)SM + wr * 16384 + lane_lo + (64 - b6);
  const char* const pB0 = (const char*)SM + 65536 + (wc >> 1) * 16384 + (wc & 1) * 8192 + lane_lo + b6;
  const char* const pB1 = (const char*)SM + 65536 + (wc >> 1) * 16384 + (wc & 1) * 8192 + lane_lo + (64 - b6);

  // ---- precomputed staging source pointers ----
  size_t soff[2];
#pragma unroll
  for (int i = 0; i < 2; i++) {
    int op = i * 8192 + tid * 16;
    int ol = op ^ (((op >> 7) & 7) << 4);
    int row = ol >> 7, colb = ol & 127;
    soff[i] = (size_t)row * K2 + (size_t)colb;
  }
  const char* srcA[2][2];
  const char* srcB[2][2];
#pragma unroll
  for (int hh = 0; hh < 2; hh++)
#pragma unroll
    for (int i = 0; i < 2; i++) {
      srcA[hh][i] = (const char*)A + (size_t)(m0 + hh * 128) * K2 + soff[i];
      srcB[hh][i] = (const char*)Bt + (size_t)(n0 + hh * 128) * K2 + soff[i];
    }
  char* const dstBase = (char*)SM;

  auto stA = [&](int buf, int half, int kt) {
#pragma unroll
    for (int i = 0; i < 2; i++)
      gl_lds16(srcA[half][i] + (size_t)kt * 128,
               dstBase + buf * 32768 + half * 16384 + i * 8192 + tid * 16);
  };
  auto stB = [&](int buf, int half, int kt) {
#pragma unroll
    for (int i = 0; i < 2; i++)
      gl_lds16(srcB[half][i] + (size_t)kt * 128,
               dstBase + 65536 + buf * 32768 + half * 16384 + i * 8192 + tid * 16);
  };

  bf16x8 af[2][2][2];   // [parity][dm][ks] - A frags, double-buffered by phase
  bf16x8 bfr[2][4][2];  // [buf][nj][ks]    - B frags, per buf
  f32x4 acc[8][4];
  const f32x4 zf = {0.f, 0.f, 0.f, 0.f};
#pragma unroll
  for (int i = 0; i < 8; i++)
#pragma unroll
    for (int j = 0; j < 4; j++) acc[i][j] = zf;

  auto rdAfrag = [&](int par, int bufsel, int ph) {
#pragma unroll
    for (int dm = 0; dm < 2; dm++) {
      af[par][dm][0] = *(const bf16x8*)(pA0 + bufsel * 32768 + (ph * 2 + dm) * 2048);
      af[par][dm][1] = *(const bf16x8*)(pA1 + bufsel * 32768 + (ph * 2 + dm) * 2048);
    }
  };
  auto rdBfrag = [&](int bufsel) {
#pragma unroll
    for (int nj = 0; nj < 4; nj++) {
      bfr[bufsel][nj][0] = *(const bf16x8*)(pB0 + bufsel * 32768 + nj * 2048);
      bfr[bufsel][nj][1] = *(const bf16x8*)(pB1 + bufsel * 32768 + nj * 2048);
    }
  };
  auto mfma16 = [&](int par, int bufsel, int ph) {
    __builtin_amdgcn_s_setprio(1);
#pragma unroll
    for (int ks = 0; ks < 2; ks++)
#pragma unroll
      for (int dm = 0; dm < 2; dm++)
#pragma unroll
        for (int nj = 0; nj < 4; nj++)
          acc[ph * 2 + dm][nj] = __builtin_amdgcn_mfma_f32_16x16x32_bf16(
              af[par][dm][ks], bfr[bufsel][nj][ks], acc[ph * 2 + dm][nj], 0, 0, 0);
    __builtin_amdgcn_s_setprio(0);
  };

  // ---- prologue: tile0 (A,B) + B(t1); preload gp0's frags ----
  stA(0, 0, 0); stA(0, 1, 0); stB(0, 0, 0); stB(0, 1, 0);
  stB(1, 0, 1); stB(1, 1, 1);
  WAITV(4);                       // tile0's 8 landed; B t1's 4 in flight
  __builtin_amdgcn_s_barrier();
  SCHEDB;
  rdBfrag(0);
  rdAfrag(0, 0, 0);               // 12 reads in flight; retired at gp0's WAITL(4)

  for (int I = 0; I < NIT - 1; ++I) {
    const int t1 = 2 * I + 1, t2 = 2 * I + 2, t3 = 2 * I + 3;
#pragma unroll
    for (int gp = 0; gp < 8; ++gp) {
      __builtin_amdgcn_s_barrier();
      SCHEDB;
      // pre-reads for NEXT phase (overlap this phase's MFMA)
      if (gp < 3)        rdAfrag((gp + 1) & 1, 0, gp + 1);
      else if (gp == 3)  { rdBfrag(1); rdAfrag(0, 1, 0); }
      else if (gp < 7)   rdAfrag((gp + 1) & 1, 1, gp - 3);
      else               { rdBfrag(0); rdAfrag(0, 0, 0); }
      // stage one half-tile
      if (gp == 0)       stA(1, 0, t1);
      else if (gp == 1)  stA(1, 1, t1);
      else if (gp == 2)  { stB(0, 0, t2); WAITV(2); }  // B(t1)+A(t1) landed
      else if (gp == 3)  stB(0, 1, t2);
      else if (gp == 4)  stA(0, 0, t2);
      else if (gp == 5)  stA(0, 1, t2);
      else if (gp == 6)  { stB(1, 0, t3); WAITV(2); }  // B(t2)+A(t2) landed
      else               stB(1, 1, t3);
      // retire PREVIOUS phase's reads (this phase's operands); leave new in flight
      if (gp == 3 || gp == 7) { WAITL(12); } else { WAITL(4); }
      SCHEDB;
      mfma16(gp & 1, gp >> 2, gp & 3);
    }
  }
  // ---- peeled last iteration (tiles 2*NIT-2 in buf0, 2*NIT-1 in buf1) ----
  {
    const int t1 = 2 * (NIT - 1) + 1;
#pragma unroll
    for (int gp = 0; gp < 8; ++gp) {
      __builtin_amdgcn_s_barrier();
      SCHEDB;
      if (gp < 3)        rdAfrag((gp + 1) & 1, 0, gp + 1);
      else if (gp == 3)  { rdBfrag(1); rdAfrag(0, 1, 0); }
      else if (gp < 7)   rdAfrag((gp + 1) & 1, 1, gp - 3);
      // gp7: no pre-read
      if (gp == 0)       stA(1, 0, t1);
      else if (gp == 1)  stA(1, 1, t1);
      else if (gp == 2)  WAITV(0);    // B(t1)+A(t1) landed (drain: tail)
      if (gp == 3)       { WAITL(12); }
      else if (gp == 7)  { WAITL(0); }
      else               { WAITL(4); }
      SCHEDB;
      mfma16(gp & 1, gp >> 2, gp & 3);
    }
  }

  if constexpr (MODE == 1) {
#pragma unroll
    for (int mi = 0; mi < 8; mi++) {
      const int mrow = m0 + wr * 128 + mi * 16 + l4 * 4;
#pragma unroll
      for (int nj = 0; nj < 4; nj++) {
        const int col = n0 + wc * 64 + nj * 16 + l16;
        const float bi = bias[col];
#pragma unroll
        for (int jj = 0; jj < 4; jj++)
          outp[(size_t)(mrow + jj) * Ndim + col] = acc[mi][nj][jj] + bi;
      }
    }
  } else {
#pragma unroll
    for (int mi = 0; mi < 8; mi++) {
      const int mrow = m0 + wr * 128 + mi * 16 + l4 * 4;
#pragma unroll
      for (int nj = 0; nj < 4; nj++) {
        const int n = n0 + wc * 64 + nj * 16 + l16;
        const float bi = bias[n];
        const int part = n >> 11;          // 0=q 1=k 2=v
        const int hcol = n & 2047;
        const int h = hcol >> 7, d = hcol & 127;
        const int dm = d & 63;
#pragma unroll
        for (int jj = 0; jj < 4; jj++) {
          const int m = mrow + jj;
          const int b = m >> 11, t = m & 2047;
          float val = acc[mi][nj][jj] + bi;
          size_t didx = (((size_t)b * NHn + h) * Tt + t) * HDn + d;
          if (part == 2) {
            v_r[didx] = f2bf(val);
          } else {
            float partner = __shfl_xor(val, 1);
            float rh = (d & 1) ? partner : -partner;
            float cs = ctab[t * 64 + dm], sn = stab[t * 64 + dm];
            float o = val * cs + rh * sn;
            if (part == 0) q_r[didx] = f2bf(o * QSCALE);
            else           k_r[didx] = f2bf(o);
          }
        }
      }
    }
  }
}

// ---------------- flash attention (causal), overlapped LDS staging -------
// (unchanged from R4/R7 config)
__global__ __launch_bounds__(256, 2) void k_attn(
    const u16* __restrict__ q_r, const u16* __restrict__ k_r,
    const u16* __restrict__ vt, u16* __restrict__ y) {
  __shared__ u16 Ks[2][64 * 128];  // [buf][key][d], swizzled, 32KB
  __shared__ u16 Vs[128 * 64];     // V^T [d][key], swizzled, 16KB
  __shared__ u16 Ps[4][32 * 72];   // per-wave P, padded stride 144B, 18KB
  const int lin = blockIdx.x;           // 0..511
  const int swz = (lin & 7) * 64 + (lin >> 3);
  const int qpair = swz & 7;            // 0..7
  const int bh = swz >> 3;              // 0..63
  const int tid = threadIdx.x, w = tid >> 6, lane = tid & 63;
  const int l16 = lane & 15, l4 = lane >> 4;
  const int b = bh >> 4, h = bh & 15;

  const u16* kbase = k_r + (size_t)bh * Tt * HDn;
  const u16* vbase = vt + (size_t)bh * HDn * Tt;
  const f32x4 zf = {0.f, 0.f, 0.f, 0.f};

  auto stageK = [&](int buf, int j) {
    const char* ksrc = (const char*)(kbase + (size_t)j * 64 * HDn);
#pragma unroll
    for (int i = 0; i < 4; i++) {
      int op = tid * 16 + i * 4096;
      int ol = op ^ (((op >> 8) & 7) << 4);   // K rows are 256B
      gl_lds16(ksrc + ol, (char*)&Ks[buf][0] + op);
    }
  };
  auto stageV = [&](int j) {
    const char* vsrc = (const char*)(vbase + (size_t)j * 64);
#pragma unroll
    for (int i = 0; i < 4; i++) {
      int op = tid * 16 + i * 4096;
      int ol = op ^ (((op >> 7) & 7) << 4);   // V^T rows are 128B
      int row = ol >> 7, colb = ol & 127;
      gl_lds16(vsrc + (size_t)row * (Tt * 2) + colb, (char*)Vs + op);
    }
  };

#pragma unroll
  for (int qsel = 0; qsel < 2; ++qsel) {
    const int qt = qsel ? (15 - qpair) : qpair;

    const u16* qbase = q_r + ((size_t)bh * Tt + qt * 128 + w * 32) * HDn;
    bf16x8 qf[2][4];
#pragma unroll
    for (int mi = 0; mi < 2; mi++)
#pragma unroll
      for (int kc = 0; kc < 4; kc++)
        qf[mi][kc] = *(const bf16x8*)(qbase + (size_t)(mi * 16 + l16) * HDn + kc * 32 + l4 * 8);

    f32x4 acc_o[2][8];
#pragma unroll
    for (int mi = 0; mi < 2; mi++)
#pragma unroll
      for (int nf = 0; nf < 8; nf++) acc_o[mi][nf] = zf;
    float mrow[2][4], lrow[2][4];
#pragma unroll
    for (int mi = 0; mi < 2; mi++)
#pragma unroll
      for (int jj = 0; jj < 4; jj++) { mrow[mi][jj] = -1e30f; lrow[mi][jj] = 0.f; }

    const int ntiles = 2 * qt + 2;
    stageK(0, 0);
    __syncthreads();                 // K(0) landed + visible
    int cur = 0;

    for (int j = 0; j < ntiles; ++j) {
      const bool more = (j + 1 < ntiles);
      stageV(j);                     // 4 loads, consumed after mid barrier
      if (more) stageK(cur ^ 1, j + 1);  // 4 loads, consumed next iteration

      // ---- S = Q K^T from Ks[cur] ----
      f32x4 s[2][4];
#pragma unroll
      for (int mi = 0; mi < 2; mi++)
#pragma unroll
        for (int nj = 0; nj < 4; nj++) s[mi][nj] = zf;
#pragma unroll
      for (int kc = 0; kc < 4; kc++) {
        bf16x8 kf[4];
#pragma unroll
        for (int nj = 0; nj < 4; nj++) {
          int row = nj * 16 + l16;
          kf[nj] = *(const bf16x8*)((const char*)&Ks[cur][0] + row * 256 +
                                    ((kc * 64 + l4 * 16) ^ ((row & 7) << 4)));
        }
        __builtin_amdgcn_s_setprio(1);
#pragma unroll
        for (int mi = 0; mi < 2; mi++)
#pragma unroll
          for (int nj = 0; nj < 4; nj++)
            s[mi][nj] = __builtin_amdgcn_mfma_f32_16x16x32_bf16(qf[mi][kc], kf[nj], s[mi][nj], 0, 0, 0);
        __builtin_amdgcn_s_setprio(0);
      }

      // ---- online softmax (wave-parallel; rescale only when max grows) ----
      const bool diag = (j >= 2 * qt);
#pragma unroll
      for (int mi = 0; mi < 2; mi++) {
#pragma unroll
        for (int jj = 0; jj < 4; jj++) {
          if (diag) {
            const int qrow = qt * 128 + w * 32 + mi * 16 + l4 * 4 + jj;
#pragma unroll
            for (int nj = 0; nj < 4; nj++) {
              const int key = j * 64 + nj * 16 + l16;
              if (key > qrow) s[mi][nj][jj] = -1e30f;
            }
          }
          float lm = fmaxf(fmaxf(s[mi][0][jj], s[mi][1][jj]), fmaxf(s[mi][2][jj], s[mi][3][jj]));
#pragma unroll
          for (int dd = 1; dd < 16; dd <<= 1) lm = fmaxf(lm, __shfl_xor(lm, dd));
          if (lm > mrow[mi][jj]) {
            const float sc = __expf(mrow[mi][jj] - lm);
            mrow[mi][jj] = lm;
            lrow[mi][jj] *= sc;
#pragma unroll
            for (int nf = 0; nf < 8; nf++) acc_o[mi][nf][jj] *= sc;
          }
          float ps = 0.f;
#pragma unroll
          for (int nj = 0; nj < 4; nj++) {
            float p = __expf(s[mi][nj][jj] - mrow[mi][jj]);
            s[mi][nj][jj] = p;
            ps += p;
          }
#pragma unroll
          for (int dd = 1; dd < 16; dd <<= 1) ps += __shfl_xor(ps, dd);
          lrow[mi][jj] += ps;
          const int prow = mi * 16 + l4 * 4 + jj;
#pragma unroll
          for (int nj = 0; nj < 4; nj++)
            Ps[w][prow * 72 + nj * 16 + l16] = f2bf(s[mi][nj][jj]);
        }
      }

      // ---- V(j) landed? (K(j+1)'s 4 loads may remain in flight) ----
      if (more) { WAITV(4); } else { WAITV(0); }
      __builtin_amdgcn_s_barrier();

      // ---- O += P V from Vs ----
#pragma unroll
      for (int kc = 0; kc < 2; kc++) {
        bf16x8 pf[2];
#pragma unroll
        for (int mi = 0; mi < 2; mi++)
          pf[mi] = *(const bf16x8*)((const char*)&Ps[w][0] + (mi * 16 + l16) * 144 + kc * 64 + l4 * 16);
        bf16x8 vf[8];
#pragma unroll
        for (int nf = 0; nf < 8; nf++) {
          int row = nf * 16 + l16;
          vf[nf] = *(const bf16x8*)((const char*)Vs + row * 128 +
                                    ((kc * 64 + l4 * 16) ^ ((row & 7) << 4)));
        }
        __builtin_amdgcn_s_setprio(1);
#pragma unroll
        for (int nf = 0; nf < 8; nf++)
#pragma unroll
          for (int mi = 0; mi < 2; mi++)
            acc_o[mi][nf] = __builtin_amdgcn_mfma_f32_16x16x32_bf16(pf[mi], vf[nf], acc_o[mi][nf], 0, 0, 0);
        __builtin_amdgcn_s_setprio(0);
      }
      __syncthreads();               // drains vmcnt(0): K(j+1) landed; reads done
      cur ^= 1;
    }

    // ---- epilogue for this q-tile ----
#pragma unroll
    for (int mi = 0; mi < 2; mi++) {
#pragma unroll
      for (int jj = 0; jj < 4; jj++) {
        const float rinv = 1.f / lrow[mi][jj];
        const int t = qt * 128 + w * 32 + mi * 16 + l4 * 4 + jj;
        u16* yrow = y + ((size_t)b * Tt + t) * Ccn + h * HDn;
#pragma unroll
        for (int nf = 0; nf < 8; nf++)
          yrow[nf * 16 + l16] = f2bf(acc_o[mi][nf][jj] * rinv);
      }
    }
    __syncthreads();                 // all epilogue reads done before next qsel stages
  }
}

// ---------------- launcher ----------------

extern "C" void kernel_launch(void* const* d_in, const int* in_sizes, int n_in,
                              void* d_out, int out_size, void* d_ws, size_t ws_size,
                              hipStream_t stream) {
  const float* x     = (const float*)d_in[0];
  const float* Wqkv  = (const float*)d_in[1];
  const float* bqkv  = (const float*)d_in[2];
  const float* Wproj = (const float*)d_in[3];
  const float* bproj = (const float*)d_in[4];
  float* out = (float*)d_out;
  char* ws = (char*)d_ws;

  size_t off = 0;
  auto alloc = [&](size_t bytes) -> char* {
    char* p = ws + off;
    off += (bytes + 255) & ~(size_t)255;
    return p;
  };
  float* ctab  = (float*)alloc((size_t)Tt * 64 * sizeof(float));
  float* stab  = (float*)alloc((size_t)Tt * 64 * sizeof(float));
  u16* xb      = (u16*)alloc((size_t)MM * Ccn * 2);
  u16* WqkvT   = (u16*)alloc((size_t)NQKV * Ccn * 2);
  u16* WprojT  = (u16*)alloc((size_t)Ccn * Ccn * 2);
  u16* q_rb    = (u16*)alloc((size_t)MM * Ccn * 2);
  u16* k_rb    = (u16*)alloc((size_t)MM * Ccn * 2);
  u16* v_rb    = (u16*)alloc((size_t)MM * Ccn * 2);
  u16* ybuf    = (u16*)alloc((size_t)MM * Ccn * 2);
  u16* vtb     = xb;  // alias: xb dead after GEMM1

  k_rope_table<<<(Tt * 64 + 255) / 256, 256, 0, stream>>>(ctab, stab);
  k_cvt<<<1024, 256, 0, stream>>>(x, xb, MM * Ccn);
  k_transpose_cvt<<<dim3(NQKV / 64, Ccn / 64), 256, 0, stream>>>(Wqkv, WqkvT, Ccn, NQKV);
  k_transpose_cvt<<<dim3(Ccn / 64, Ccn / 64), 256, 0, stream>>>(Wproj, WprojT, Ccn, Ccn);

  k_gemm256<0><<<dim3((MM / 256) * (NQKV / 256)), 512, 0, stream>>>(
      xb, WqkvT, NQKV, NQKV / 256, bqkv, q_rb, k_rb, v_rb, ctab, stab, nullptr);

  k_vtrans<<<dim3(Tt / 64, HDn / 64, Bb * NHn), 256, 0, stream>>>(v_rb, vtb);

  k_attn<<<dim3(512), 256, 0, stream>>>(q_rb, k_rb, vtb, ybuf);

  k_gemm256<1><<<dim3((MM / 256) * (Ccn / 256)), 512, 0, stream>>>(
      ybuf, WprojT, Ccn, Ccn / 256, bproj, nullptr, nullptr, nullptr, nullptr, nullptr, out);
}

// Round 9
// 510.134 us; speedup vs baseline: 1.1029x; 1.1029x over previous
//
#include <hip/hip_runtime.h>
#include <hip/hip_bf16.h>
#include <stdint.h>

#define DEV __device__ __forceinline__
#define WAITV(n) asm volatile("s_waitcnt vmcnt(" #n ")" ::: "memory")
#define WAITL(n) asm volatile("s_waitcnt lgkmcnt(" #n ")" ::: "memory")
#define SCHEDB __builtin_amdgcn_sched_barrier(0)

typedef __attribute__((ext_vector_type(4))) float f32x4;
typedef __attribute__((ext_vector_type(8))) short bf16x8;
typedef unsigned short u16;

constexpr int Bb = 4, Tt = 2048, Ccn = 2048, NHn = 16, HDn = 128;
constexpr int MM = Bb * Tt;          // 8192
constexpr int NQKV = 3 * Ccn;        // 6144
constexpr int KD = 2048;             // K dim for BOTH GEMMs
constexpr size_t K2 = (size_t)KD * 2;  // row stride bytes
constexpr size_t HKB = 128 * K2;       // half-tile row block bytes
constexpr float QSCALE = 0.08838834764831845f;  // 1/sqrt(128)

DEV u16 f2bf(float f) {
  __hip_bfloat16 h = __float2bfloat16(f);
  return *reinterpret_cast<u16*>(&h);
}

DEV void gl_lds16(const void* g, void* l) {
  __builtin_amdgcn_global_load_lds(
      (const __attribute__((address_space(1))) void*)g,
      (__attribute__((address_space(3))) void*)l, 16, 0, 0);
}

// ---------------- prep kernels ----------------

__global__ void k_rope_table(float* __restrict__ ct, float* __restrict__ st) {
  int idx = blockIdx.x * blockDim.x + threadIdx.x;
  if (idx >= Tt * 64) return;
  int t = idx >> 6, j = idx & 63;
  float invf = expf(-(float)j * 0.14391157f);  // ln(10000)/64
  float a = (float)t * invf;
  ct[idx] = cosf(a);
  st[idx] = sinf(a);
}

__global__ void k_cvt(const float* __restrict__ in, u16* __restrict__ out, int n) {
  int i = blockIdx.x * blockDim.x + threadIdx.x;
  int stride = gridDim.x * blockDim.x;
  int n4 = n >> 2;
  for (int idx = i; idx < n4; idx += stride) {
    float4 v = ((const float4*)in)[idx];
    ushort4 o;
    o.x = f2bf(v.x); o.y = f2bf(v.y); o.z = f2bf(v.z); o.w = f2bf(v.w);
    ((ushort4*)out)[idx] = o;
  }
}

// in: fp32 [R][NC]  ->  out: bf16 [NC][R]
__global__ void k_transpose_cvt(const float* __restrict__ in, u16* __restrict__ out,
                                int R, int NC) {
  __shared__ u16 tile[64][72];
  int tr = blockIdx.y * 64, tc = blockIdx.x * 64;
  int r = threadIdx.x >> 2, c = (threadIdx.x & 3) * 16;
  const float* src = in + (size_t)(tr + r) * NC + tc + c;
#pragma unroll
  for (int i = 0; i < 16; i++) tile[r][c + i] = f2bf(src[i]);
  __syncthreads();
  u16* dst = out + (size_t)(tc + r) * R + tr + c;
#pragma unroll
  for (int i = 0; i < 16; i++) dst[i] = tile[c + i][r];
}

// v [BH][T][D] -> vt [BH][D][T]
__global__ void k_vtrans(const u16* __restrict__ v, u16* __restrict__ vt) {
  __shared__ u16 tile[64][72];
  int bh = blockIdx.z;
  int t0 = blockIdx.x * 64, d0 = blockIdx.y * 64;
  int r = threadIdx.x >> 2, c = (threadIdx.x & 3) * 16;
  const u16* src = v + ((size_t)bh * Tt + t0) * HDn + d0;
#pragma unroll
  for (int i = 0; i < 16; i++) tile[r][c + i] = src[(size_t)r * HDn + c + i];
  __syncthreads();
  u16* dst = vt + ((size_t)bh * HDn + d0) * Tt + t0;
#pragma unroll
  for (int i = 0; i < 16; i++) dst[(size_t)r * Tt + c + i] = tile[c + i][r];
}

// ---------------- 256x256 8-phase GEMM, register-pipelined (slim) --------
// R8 lesson: launch_bounds(512,2) => 256 reg/wave total; acc=128 AGPR leaves
// 128 arch VGPR. R8's double-buffered B frags spilled (WRITE_SIZE +62MB).
// Slim pipeline: af[2][2][2] (32 VGPR) pre-read 1 phase ahead every phase;
// bfr[4][2] (32 VGPR) SINGLE-buffered, refilled at gp3/gp7 AFTER the MFMA
// consumed them (register WAR keeps order; reads fly across the barrier).
// lgkm ledger: every phase issues 4 af reads (+8 bfr at gp3/gp7 post-MFMA);
// at each phase entry the previous phase's reads are exactly this phase's
// operands -> uniform WAITL(4) (leaves this phase's 4 pre-reads in flight).
// vmcnt: WAITV(2) at gp2/gp6 retires prior tile's 8 stages. One barrier per
// phase. Hazards: every region restaged >=1 barrier after reader retirement.

template <int MODE>
__global__ __launch_bounds__(512, 2) void k_gemm256(
    const u16* __restrict__ A, const u16* __restrict__ Bt,
    int Ndim, int NBX,
    const float* __restrict__ bias,
    u16* __restrict__ q_r, u16* __restrict__ k_r, u16* __restrict__ v_r,
    const float* __restrict__ ctab, const float* __restrict__ stab,
    float* __restrict__ outp) {
  __shared__ __align__(16) u16 SM[65536];   // 128KB: A 64KB | B 64KB
  const int tid = threadIdx.x;
  const int w = tid >> 6, lane = tid & 63;
  const int l16 = lane & 15, l4 = lane >> 4;
  const int wr = w >> 2, wc = w & 3;
  const int bid = blockIdx.x, nwg = gridDim.x;
  const int swz = (bid & 7) * (nwg >> 3) + (bid >> 3);   // XCD-aware
  const int by = swz / NBX, bx = swz % NBX;
  const int m0 = by * 256, n0 = bx * 256;
  constexpr int NT = KD >> 6;      // 32
  constexpr int NIT = NT >> 1;     // 16

  // ---- precomputed LDS read bases (lane-constant) ----
  const int Mx = (l16 & 7) << 4;
  const int b6 = Mx & 64;
  const int lane_lo = l16 * 128 + ((l4 * 16) ^ (Mx & 48));
  const char* const pA0 = (const char*)SM + wr * 16384 + lane_lo + b6;
  const char* const pA1 = (const char*)SM + wr * 16384 + lane_lo + (64 - b6);
  const char* const pB0 = (const char*)SM + 65536 + (wc >> 1) * 16384 + (wc & 1) * 8192 + lane_lo + b6;
  const char* const pB1 = (const char*)SM + 65536 + (wc >> 1) * 16384 + (wc & 1) * 8192 + lane_lo + (64 - b6);

  // ---- staging: uniform base + 32-bit lane offset (saddr+voffset form) ----
  uint32_t soff[2];
#pragma unroll
  for (int i = 0; i < 2; i++) {
    int op = i * 8192 + tid * 16;
    int ol = op ^ (((op >> 7) & 7) << 4);
    int row = ol >> 7, colb = ol & 127;
    soff[i] = (uint32_t)(row * (int)K2 + colb);
  }
  const char* const Ab = (const char*)A + (size_t)m0 * K2;
  const char* const Bbp = (const char*)Bt + (size_t)n0 * K2;
  char* const dstBase = (char*)SM;

  auto stA = [&](int buf, int half, int kt) {
#pragma unroll
    for (int i = 0; i < 2; i++)
      gl_lds16(Ab + (size_t)half * HKB + (size_t)kt * 128 + soff[i],
               dstBase + buf * 32768 + half * 16384 + i * 8192 + tid * 16);
  };
  auto stB = [&](int buf, int half, int kt) {
#pragma unroll
    for (int i = 0; i < 2; i++)
      gl_lds16(Bbp + (size_t)half * HKB + (size_t)kt * 128 + soff[i],
               dstBase + 65536 + buf * 32768 + half * 16384 + i * 8192 + tid * 16);
  };

  bf16x8 af[2][2][2];   // [parity][dm][ks] : 32 VGPR, pre-read 1 phase ahead
  bf16x8 bfr[4][2];     // [nj][ks]         : 32 VGPR, single-buffered
  f32x4 acc[8][4];
  const f32x4 zf = {0.f, 0.f, 0.f, 0.f};
#pragma unroll
  for (int i = 0; i < 8; i++)
#pragma unroll
    for (int j = 0; j < 4; j++) acc[i][j] = zf;

  auto rdAfrag = [&](int par, int bufsel, int ph) {
#pragma unroll
    for (int dm = 0; dm < 2; dm++) {
      af[par][dm][0] = *(const bf16x8*)(pA0 + bufsel * 32768 + (ph * 2 + dm) * 2048);
      af[par][dm][1] = *(const bf16x8*)(pA1 + bufsel * 32768 + (ph * 2 + dm) * 2048);
    }
  };
  auto rdBfrag = [&](int bufsel) {
#pragma unroll
    for (int nj = 0; nj < 4; nj++) {
      bfr[nj][0] = *(const bf16x8*)(pB0 + bufsel * 32768 + nj * 2048);
      bfr[nj][1] = *(const bf16x8*)(pB1 + bufsel * 32768 + nj * 2048);
    }
  };
  auto mfma16 = [&](int par, int ph) {
    __builtin_amdgcn_s_setprio(1);
#pragma unroll
    for (int ks = 0; ks < 2; ks++)
#pragma unroll
      for (int dm = 0; dm < 2; dm++)
#pragma unroll
        for (int nj = 0; nj < 4; nj++)
          acc[ph * 2 + dm][nj] = __builtin_amdgcn_mfma_f32_16x16x32_bf16(
              af[par][dm][ks], bfr[nj][ks], acc[ph * 2 + dm][nj], 0, 0, 0);
    __builtin_amdgcn_s_setprio(0);
  };

  // ---- prologue: tile0 (A,B) + B(t1); preload gp0's frags ----
  stA(0, 0, 0); stA(0, 1, 0); stB(0, 0, 0); stB(0, 1, 0);
  stB(1, 0, 1); stB(1, 1, 1);
  WAITV(4);                       // tile0's 8 landed; B(t1)'s 4 in flight
  __builtin_amdgcn_s_barrier();
  SCHEDB;
  rdBfrag(0);
  rdAfrag(0, 0, 0);               // 12 in flight; retired at gp0's WAITL(4)

  for (int I = 0; I < NIT - 1; ++I) {
    const int t1 = 2 * I + 1, t2 = 2 * I + 2, t3 = 2 * I + 3;
#pragma unroll
    for (int gp = 0; gp < 8; ++gp) {
      __builtin_amdgcn_s_barrier();
      SCHEDB;
      {  // pre-read af for NEXT phase (flies under this phase's MFMA)
        const int ng = (gp + 1) & 7;
        rdAfrag((gp + 1) & 1, ng >> 2, ng & 3);
      }
      // stage one half-tile
      if (gp == 0)       stA(1, 0, t1);
      else if (gp == 1)  stA(1, 1, t1);
      else if (gp == 2)  { stB(0, 0, t2); WAITV(2); }  // B(t1)+A(t1) landed
      else if (gp == 3)  stB(0, 1, t2);
      else if (gp == 4)  stA(0, 0, t2);
      else if (gp == 5)  stA(0, 1, t2);
      else if (gp == 6)  { stB(1, 0, t3); WAITV(2); }  // B(t2)+A(t2) landed
      else               stB(1, 1, t3);
      WAITL(4);          // retire prev phase's reads (this phase's operands)
      SCHEDB;
      mfma16(gp & 1, gp & 3);
      if (gp == 3)      { rdBfrag(1); SCHEDB; }  // post-MFMA: refill B for buf1
      else if (gp == 7) { rdBfrag(0); SCHEDB; }  // refill B for next iter buf0
    }
  }
  // ---- peeled last iteration (tiles 2*NIT-2 buf0, 2*NIT-1 buf1) ----
  {
    const int t1 = 2 * (NIT - 1) + 1;
#pragma unroll
    for (int gp = 0; gp < 8; ++gp) {
      __builtin_amdgcn_s_barrier();
      SCHEDB;
      if (gp < 7) { const int ng = gp + 1; rdAfrag((gp + 1) & 1, ng >> 2, ng & 3); }
      if (gp == 0)       stA(1, 0, t1);
      else if (gp == 1)  stA(1, 1, t1);
      else if (gp == 2)  WAITV(0);    // A(t1)+B(t1) landed (tail drain)
      if (gp == 7) { WAITL(0); } else { WAITL(4); }
      SCHEDB;
      mfma16(gp & 1, gp & 3);
      if (gp == 3) { rdBfrag(1); SCHEDB; }
    }
  }

  if constexpr (MODE == 1) {
#pragma unroll
    for (int mi = 0; mi < 8; mi++) {
      const int mrow = m0 + wr * 128 + mi * 16 + l4 * 4;
#pragma unroll
      for (int nj = 0; nj < 4; nj++) {
        const int col = n0 + wc * 64 + nj * 16 + l16;
        const float bi = bias[col];
#pragma unroll
        for (int jj = 0; jj < 4; jj++)
          outp[(size_t)(mrow + jj) * Ndim + col] = acc[mi][nj][jj] + bi;
      }
    }
  } else {
#pragma unroll
    for (int mi = 0; mi < 8; mi++) {
      const int mrow = m0 + wr * 128 + mi * 16 + l4 * 4;
#pragma unroll
      for (int nj = 0; nj < 4; nj++) {
        const int n = n0 + wc * 64 + nj * 16 + l16;
        const float bi = bias[n];
        const int part = n >> 11;          // 0=q 1=k 2=v
        const int hcol = n & 2047;
        const int h = hcol >> 7, d = hcol & 127;
        const int dm = d & 63;
#pragma unroll
        for (int jj = 0; jj < 4; jj++) {
          const int m = mrow + jj;
          const int b = m >> 11, t = m & 2047;
          float val = acc[mi][nj][jj] + bi;
          size_t didx = (((size_t)b * NHn + h) * Tt + t) * HDn + d;
          if (part == 2) {
            v_r[didx] = f2bf(val);
          } else {
            float partner = __shfl_xor(val, 1);
            float rh = (d & 1) ? partner : -partner;
            float cs = ctab[t * 64 + dm], sn = stab[t * 64 + dm];
            float o = val * cs + rh * sn;
            if (part == 0) q_r[didx] = f2bf(o * QSCALE);
            else           k_r[didx] = f2bf(o);
          }
        }
      }
    }
  }
}

// ---------------- flash attention (causal), overlapped LDS staging -------
// (unchanged from R4/R7 config)
__global__ __launch_bounds__(256, 2) void k_attn(
    const u16* __restrict__ q_r, const u16* __restrict__ k_r,
    const u16* __restrict__ vt, u16* __restrict__ y) {
  __shared__ u16 Ks[2][64 * 128];  // [buf][key][d], swizzled, 32KB
  __shared__ u16 Vs[128 * 64];     // V^T [d][key], swizzled, 16KB
  __shared__ u16 Ps[4][32 * 72];   // per-wave P, padded stride 144B, 18KB
  const int lin = blockIdx.x;           // 0..511
  const int swz = (lin & 7) * 64 + (lin >> 3);
  const int qpair = swz & 7;            // 0..7
  const int bh = swz >> 3;              // 0..63
  const int tid = threadIdx.x, w = tid >> 6, lane = tid & 63;
  const int l16 = lane & 15, l4 = lane >> 4;
  const int b = bh >> 4, h = bh & 15;

  const u16* kbase = k_r + (size_t)bh * Tt * HDn;
  const u16* vbase = vt + (size_t)bh * HDn * Tt;
  const f32x4 zf = {0.f, 0.f, 0.f, 0.f};

  auto stageK = [&](int buf, int j) {
    const char* ksrc = (const char*)(kbase + (size_t)j * 64 * HDn);
#pragma unroll
    for (int i = 0; i < 4; i++) {
      int op = tid * 16 + i * 4096;
      int ol = op ^ (((op >> 8) & 7) << 4);   // K rows are 256B
      gl_lds16(ksrc + ol, (char*)&Ks[buf][0] + op);
    }
  };
  auto stageV = [&](int j) {
    const char* vsrc = (const char*)(vbase + (size_t)j * 64);
#pragma unroll
    for (int i = 0; i < 4; i++) {
      int op = tid * 16 + i * 4096;
      int ol = op ^ (((op >> 7) & 7) << 4);   // V^T rows are 128B
      int row = ol >> 7, colb = ol & 127;
      gl_lds16(vsrc + (size_t)row * (Tt * 2) + colb, (char*)Vs + op);
    }
  };

#pragma unroll
  for (int qsel = 0; qsel < 2; ++qsel) {
    const int qt = qsel ? (15 - qpair) : qpair;

    const u16* qbase = q_r + ((size_t)bh * Tt + qt * 128 + w * 32) * HDn;
    bf16x8 qf[2][4];
#pragma unroll
    for (int mi = 0; mi < 2; mi++)
#pragma unroll
      for (int kc = 0; kc < 4; kc++)
        qf[mi][kc] = *(const bf16x8*)(qbase + (size_t)(mi * 16 + l16) * HDn + kc * 32 + l4 * 8);

    f32x4 acc_o[2][8];
#pragma unroll
    for (int mi = 0; mi < 2; mi++)
#pragma unroll
      for (int nf = 0; nf < 8; nf++) acc_o[mi][nf] = zf;
    float mrow[2][4], lrow[2][4];
#pragma unroll
    for (int mi = 0; mi < 2; mi++)
#pragma unroll
      for (int jj = 0; jj < 4; jj++) { mrow[mi][jj] = -1e30f; lrow[mi][jj] = 0.f; }

    const int ntiles = 2 * qt + 2;
    stageK(0, 0);
    __syncthreads();                 // K(0) landed + visible
    int cur = 0;

    for (int j = 0; j < ntiles; ++j) {
      const bool more = (j + 1 < ntiles);
      stageV(j);                     // 4 loads, consumed after mid barrier
      if (more) stageK(cur ^ 1, j + 1);  // 4 loads, consumed next iteration

      // ---- S = Q K^T from Ks[cur] ----
      f32x4 s[2][4];
#pragma unroll
      for (int mi = 0; mi < 2; mi++)
#pragma unroll
        for (int nj = 0; nj < 4; nj++) s[mi][nj] = zf;
#pragma unroll
      for (int kc = 0; kc < 4; kc++) {
        bf16x8 kf[4];
#pragma unroll
        for (int nj = 0; nj < 4; nj++) {
          int row = nj * 16 + l16;
          kf[nj] = *(const bf16x8*)((const char*)&Ks[cur][0] + row * 256 +
                                    ((kc * 64 + l4 * 16) ^ ((row & 7) << 4)));
        }
        __builtin_amdgcn_s_setprio(1);
#pragma unroll
        for (int mi = 0; mi < 2; mi++)
#pragma unroll
          for (int nj = 0; nj < 4; nj++)
            s[mi][nj] = __builtin_amdgcn_mfma_f32_16x16x32_bf16(qf[mi][kc], kf[nj], s[mi][nj], 0, 0, 0);
        __builtin_amdgcn_s_setprio(0);
      }

      // ---- online softmax (wave-parallel; rescale only when max grows) ----
      const bool diag = (j >= 2 * qt);
#pragma unroll
      for (int mi = 0; mi < 2; mi++) {
#pragma unroll
        for (int jj = 0; jj < 4; jj++) {
          if (diag) {
            const int qrow = qt * 128 + w * 32 + mi * 16 + l4 * 4 + jj;
#pragma unroll
            for (int nj = 0; nj < 4; nj++) {
              const int key = j * 64 + nj * 16 + l16;
              if (key > qrow) s[mi][nj][jj] = -1e30f;
            }
          }
          float lm = fmaxf(fmaxf(s[mi][0][jj], s[mi][1][jj]), fmaxf(s[mi][2][jj], s[mi][3][jj]));
#pragma unroll
          for (int dd = 1; dd < 16; dd <<= 1) lm = fmaxf(lm, __shfl_xor(lm, dd));
          if (lm > mrow[mi][jj]) {
            const float sc = __expf(mrow[mi][jj] - lm);
            mrow[mi][jj] = lm;
            lrow[mi][jj] *= sc;
#pragma unroll
            for (int nf = 0; nf < 8; nf++) acc_o[mi][nf][jj] *= sc;
          }
          float ps = 0.f;
#pragma unroll
          for (int nj = 0; nj < 4; nj++) {
            float p = __expf(s[mi][nj][jj] - mrow[mi][jj]);
            s[mi][nj][jj] = p;
            ps += p;
          }
#pragma unroll
          for (int dd = 1; dd < 16; dd <<= 1) ps += __shfl_xor(ps, dd);
          lrow[mi][jj] += ps;
          const int prow = mi * 16 + l4 * 4 + jj;
#pragma unroll
          for (int nj = 0; nj < 4; nj++)
            Ps[w][prow * 72 + nj * 16 + l16] = f2bf(s[mi][nj][jj]);
        }
      }

      // ---- V(j) landed? (K(j+1)'s 4 loads may remain in flight) ----
      if (more) { WAITV(4); } else { WAITV(0); }
      __builtin_amdgcn_s_barrier();

      // ---- O += P V from Vs ----
#pragma unroll
      for (int kc = 0; kc < 2; kc++) {
        bf16x8 pf[2];
#pragma unroll
        for (int mi = 0; mi < 2; mi++)
          pf[mi] = *(const bf16x8*)((const char*)&Ps[w][0] + (mi * 16 + l16) * 144 + kc * 64 + l4 * 16);
        bf16x8 vf[8];
#pragma unroll
        for (int nf = 0; nf < 8; nf++) {
          int row = nf * 16 + l16;
          vf[nf] = *(const bf16x8*)((const char*)Vs + row * 128 +
                                    ((kc * 64 + l4 * 16) ^ ((row & 7) << 4)));
        }
        __builtin_amdgcn_s_setprio(1);
#pragma unroll
        for (int nf = 0; nf < 8; nf++)
#pragma unroll
          for (int mi = 0; mi < 2; mi++)
            acc_o[mi][nf] = __builtin_amdgcn_mfma_f32_16x16x32_bf16(pf[mi], vf[nf], acc_o[mi][nf], 0, 0, 0);
        __builtin_amdgcn_s_setprio(0);
      }
      __syncthreads();               // drains vmcnt(0): K(j+1) landed; reads done
      cur ^= 1;
    }

    // ---- epilogue for this q-tile ----
#pragma unroll
    for (int mi = 0; mi < 2; mi++) {
#pragma unroll
      for (int jj = 0; jj < 4; jj++) {
        const float rinv = 1.f / lrow[mi][jj];
        const int t = qt * 128 + w * 32 + mi * 16 + l4 * 4 + jj;
        u16* yrow = y + ((size_t)b * Tt + t) * Ccn + h * HDn;
#pragma unroll
        for (int nf = 0; nf < 8; nf++)
          yrow[nf * 16 + l16] = f2bf(acc_o[mi][nf][jj] * rinv);
      }
    }
    __syncthreads();                 // all epilogue reads done before next qsel stages
  }
}

// ---------------- launcher ----------------

extern "C" void kernel_launch(void* const* d_in, const int* in_sizes, int n_in,
                              void* d_out, int out_size, void* d_ws, size_t ws_size,
                              hipStream_t stream) {
  const float* x     = (const float*)d_in[0];
  const float* Wqkv  = (const float*)d_in[1];
  const float* bqkv  = (const float*)d_in[2];
  const float* Wproj = (const float*)d_in[3];
  const float* bproj = (const float*)d_in[4];
  float* out = (float*)d_out;
  char* ws = (char*)d_ws;

  size_t off = 0;
  auto alloc = [&](size_t bytes) -> char* {
    char* p = ws + off;
    off += (bytes + 255) & ~(size_t)255;
    return p;
  };
  float* ctab  = (float*)alloc((size_t)Tt * 64 * sizeof(float));
  float* stab  = (float*)alloc((size_t)Tt * 64 * sizeof(float));
  u16* xb      = (u16*)alloc((size_t)MM * Ccn * 2);
  u16* WqkvT   = (u16*)alloc((size_t)NQKV * Ccn * 2);
  u16* WprojT  = (u16*)alloc((size_t)Ccn * Ccn * 2);
  u16* q_rb    = (u16*)alloc((size_t)MM * Ccn * 2);
  u16* k_rb    = (u16*)alloc((size_t)MM * Ccn * 2);
  u16* v_rb    = (u16*)alloc((size_t)MM * Ccn * 2);
  u16* ybuf    = (u16*)alloc((size_t)MM * Ccn * 2);
  u16* vtb     = xb;  // alias: xb dead after GEMM1

  k_rope_table<<<(Tt * 64 + 255) / 256, 256, 0, stream>>>(ctab, stab);
  k_cvt<<<1024, 256, 0, stream>>>(x, xb, MM * Ccn);
  k_transpose_cvt<<<dim3(NQKV / 64, Ccn / 64), 256, 0, stream>>>(Wqkv, WqkvT, Ccn, NQKV);
  k_transpose_cvt<<<dim3(Ccn / 64, Ccn / 64), 256, 0, stream>>>(Wproj, WprojT, Ccn, Ccn);

  k_gemm256<0><<<dim3((MM / 256) * (NQKV / 256)), 512, 0, stream>>>(
      xb, WqkvT, NQKV, NQKV / 256, bqkv, q_rb, k_rb, v_rb, ctab, stab, nullptr);

  k_vtrans<<<dim3(Tt / 64, HDn / 64, Bb * NHn), 256, 0, stream>>>(v_rb, vtb);

  k_attn<<<dim3(512), 256, 0, stream>>>(q_rb, k_rb, vtb, ybuf);

  k_gemm256<1><<<dim3((MM / 256) * (Ccn / 256)), 512, 0, stream>>>(
      ybuf, WprojT, Ccn, Ccn / 256, bproj, nullptr, nullptr, nullptr, nullptr, nullptr, out);
}

// Round 10
// 444.817 us; speedup vs baseline: 1.2648x; 1.1468x over previous
//
#include <hip/hip_runtime.h>
#include <hip/hip_bf16.h>
#include <stdint.h>

#define DEV __device__ __forceinline__
#define WAITV(n) asm volatile("s_waitcnt vmcnt(" #n ")" ::: "memory")
#define WAITL(n) asm volatile("s_waitcnt lgkmcnt(" #n ")" ::: "memory")
#define SCHEDB __builtin_amdgcn_sched_barrier(0)

typedef __attribute__((ext_vector_type(4))) float f32x4;
typedef __attribute__((ext_vector_type(8))) short bf16x8;
typedef unsigned short u16;

constexpr int Bb = 4, Tt = 2048, Ccn = 2048, NHn = 16, HDn = 128;
constexpr int MM = Bb * Tt;          // 8192
constexpr int NQKV = 3 * Ccn;        // 6144
constexpr int KD = 2048;             // K dim for BOTH GEMMs
constexpr size_t K2 = (size_t)KD * 2;  // row stride bytes
constexpr size_t HKB = 128 * K2;       // half-tile row block bytes
constexpr float QSCALE = 0.08838834764831845f;  // 1/sqrt(128)

DEV u16 f2bf(float f) {
  __hip_bfloat16 h = __float2bfloat16(f);
  return *reinterpret_cast<u16*>(&h);
}

DEV void gl_lds16(const void* g, void* l) {
  __builtin_amdgcn_global_load_lds(
      (const __attribute__((address_space(1))) void*)g,
      (__attribute__((address_space(3))) void*)l, 16, 0, 0);
}

// ---------------- merged prep kernel ----------------
// grid 5632 x 256: [0,1024) cvt x -> bf16; [1024,4096) transpose Wqkv;
// [4096,5120) transpose Wproj; [5120,5632) rope table.
__global__ void k_prep(const float* __restrict__ x, u16* __restrict__ xb,
                       const float* __restrict__ Wqkv, u16* __restrict__ WqkvT,
                       const float* __restrict__ Wproj, u16* __restrict__ WprojT,
                       float* __restrict__ ct, float* __restrict__ st) {
  __shared__ u16 tile[64][72];
  const int bid = blockIdx.x, tid = threadIdx.x;
  if (bid < 1024) {
    const int n4 = (MM * Ccn) >> 2;
    for (int idx = bid * 256 + tid; idx < n4; idx += 1024 * 256) {
      float4 v = ((const float4*)x)[idx];
      ushort4 o;
      o.x = f2bf(v.x); o.y = f2bf(v.y); o.z = f2bf(v.z); o.w = f2bf(v.w);
      ((ushort4*)xb)[idx] = o;
    }
  } else if (bid < 5120) {
    const float* in; u16* out; int NC, bx, by;
    if (bid < 4096) {
      int t = bid - 1024; in = Wqkv; out = WqkvT; NC = NQKV; bx = t % 96; by = t / 96;
    } else {
      int t = bid - 4096; in = Wproj; out = WprojT; NC = Ccn; bx = t & 31; by = t >> 5;
    }
    const int R = 2048;
    int tr = by * 64, tc = bx * 64;
    int r = tid >> 2, c = (tid & 3) * 16;
    const float* src = in + (size_t)(tr + r) * NC + tc + c;
#pragma unroll
    for (int i = 0; i < 16; i++) tile[r][c + i] = f2bf(src[i]);
    __syncthreads();
    u16* dst = out + (size_t)(tc + r) * R + tr + c;
#pragma unroll
    for (int i = 0; i < 16; i++) dst[i] = tile[c + i][r];
  } else {
    int idx = (bid - 5120) * 256 + tid;   // < 131072 = Tt*64
    int t = idx >> 6, j = idx & 63;
    float invf = expf(-(float)j * 0.14391157f);  // ln(10000)/64
    float a = (float)t * invf;
    ct[idx] = cosf(a);
    st[idx] = sinf(a);
  }
}

// ---------------- 256x256 8-phase GEMM, register-pipelined (slim) --------
// R9 base (best: 860 TF). Change: WAITV(2) moved from mid-gp2/gp6 (before
// that phase's MFMA) to END of gp2/gp6 (after MFMA) — still before the
// gp3/gp7 barrier (required: vmcnt is per-wave; all waves must certify
// their staged loads before any wave's post-barrier ds_read). Gains ~620cy
// of latency slack per wait at zero structural cost.
// MODE 0 epilogue now also writes V DIRECTLY TRANSPOSED (vt [BH][D][T],
// packed ushort4 over 4 consecutive t) — k_vtrans kernel eliminated.

template <int MODE>
__global__ __launch_bounds__(512, 2) void k_gemm256(
    const u16* __restrict__ A, const u16* __restrict__ Bt,
    int Ndim, int NBX,
    const float* __restrict__ bias,
    u16* __restrict__ q_r, u16* __restrict__ k_r, u16* __restrict__ vt,
    const float* __restrict__ ctab, const float* __restrict__ stab,
    float* __restrict__ outp) {
  __shared__ __align__(16) u16 SM[65536];   // 128KB: A 64KB | B 64KB
  const int tid = threadIdx.x;
  const int w = tid >> 6, lane = tid & 63;
  const int l16 = lane & 15, l4 = lane >> 4;
  const int wr = w >> 2, wc = w & 3;
  const int bid = blockIdx.x, nwg = gridDim.x;
  const int swz = (bid & 7) * (nwg >> 3) + (bid >> 3);   // XCD-aware
  const int by = swz / NBX, bx = swz % NBX;
  const int m0 = by * 256, n0 = bx * 256;
  constexpr int NT = KD >> 6;      // 32
  constexpr int NIT = NT >> 1;     // 16

  // ---- precomputed LDS read bases (lane-constant) ----
  const int Mx = (l16 & 7) << 4;
  const int b6 = Mx & 64;
  const int lane_lo = l16 * 128 + ((l4 * 16) ^ (Mx & 48));
  const char* const pA0 = (const char*)SM + wr * 16384 + lane_lo + b6;
  const char* const pA1 = (const char*)SM + wr * 16384 + lane_lo + (64 - b6);
  const char* const pB0 = (const char*)SM + 65536 + (wc >> 1) * 16384 + (wc & 1) * 8192 + lane_lo + b6;
  const char* const pB1 = (const char*)SM + 65536 + (wc >> 1) * 16384 + (wc & 1) * 8192 + lane_lo + (64 - b6);

  // ---- staging: uniform base + 32-bit lane offset ----
  uint32_t soff[2];
#pragma unroll
  for (int i = 0; i < 2; i++) {
    int op = i * 8192 + tid * 16;
    int ol = op ^ (((op >> 7) & 7) << 4);
    int row = ol >> 7, colb = ol & 127;
    soff[i] = (uint32_t)(row * (int)K2 + colb);
  }
  const char* const Ab = (const char*)A + (size_t)m0 * K2;
  const char* const Bbp = (const char*)Bt + (size_t)n0 * K2;
  char* const dstBase = (char*)SM;

  auto stA = [&](int buf, int half, int kt) {
#pragma unroll
    for (int i = 0; i < 2; i++)
      gl_lds16(Ab + (size_t)half * HKB + (size_t)kt * 128 + soff[i],
               dstBase + buf * 32768 + half * 16384 + i * 8192 + tid * 16);
  };
  auto stB = [&](int buf, int half, int kt) {
#pragma unroll
    for (int i = 0; i < 2; i++)
      gl_lds16(Bbp + (size_t)half * HKB + (size_t)kt * 128 + soff[i],
               dstBase + 65536 + buf * 32768 + half * 16384 + i * 8192 + tid * 16);
  };

  bf16x8 af[2][2][2];   // [parity][dm][ks] : pre-read 1 phase ahead
  bf16x8 bfr[4][2];     // [nj][ks]         : single-buffered
  f32x4 acc[8][4];
  const f32x4 zf = {0.f, 0.f, 0.f, 0.f};
#pragma unroll
  for (int i = 0; i < 8; i++)
#pragma unroll
    for (int j = 0; j < 4; j++) acc[i][j] = zf;

  auto rdAfrag = [&](int par, int bufsel, int ph) {
#pragma unroll
    for (int dm = 0; dm < 2; dm++) {
      af[par][dm][0] = *(const bf16x8*)(pA0 + bufsel * 32768 + (ph * 2 + dm) * 2048);
      af[par][dm][1] = *(const bf16x8*)(pA1 + bufsel * 32768 + (ph * 2 + dm) * 2048);
    }
  };
  auto rdBfrag = [&](int bufsel) {
#pragma unroll
    for (int nj = 0; nj < 4; nj++) {
      bfr[nj][0] = *(const bf16x8*)(pB0 + bufsel * 32768 + nj * 2048);
      bfr[nj][1] = *(const bf16x8*)(pB1 + bufsel * 32768 + nj * 2048);
    }
  };
  auto mfma16 = [&](int par, int ph) {
    __builtin_amdgcn_s_setprio(1);
#pragma unroll
    for (int ks = 0; ks < 2; ks++)
#pragma unroll
      for (int dm = 0; dm < 2; dm++)
#pragma unroll
        for (int nj = 0; nj < 4; nj++)
          acc[ph * 2 + dm][nj] = __builtin_amdgcn_mfma_f32_16x16x32_bf16(
              af[par][dm][ks], bfr[nj][ks], acc[ph * 2 + dm][nj], 0, 0, 0);
    __builtin_amdgcn_s_setprio(0);
  };

  // ---- prologue: tile0 (A,B) + B(t1); preload gp0's frags ----
  stA(0, 0, 0); stA(0, 1, 0); stB(0, 0, 0); stB(0, 1, 0);
  stB(1, 0, 1); stB(1, 1, 1);
  WAITV(4);                       // tile0's 8 landed; B(t1)'s 4 in flight
  __builtin_amdgcn_s_barrier();
  SCHEDB;
  rdBfrag(0);
  rdAfrag(0, 0, 0);               // 12 in flight; retired at gp0's WAITL(4)

  for (int I = 0; I < NIT - 1; ++I) {
    const int t1 = 2 * I + 1, t2 = 2 * I + 2, t3 = 2 * I + 3;
#pragma unroll
    for (int gp = 0; gp < 8; ++gp) {
      __builtin_amdgcn_s_barrier();
      SCHEDB;
      {  // pre-read af for NEXT phase (flies under this phase's MFMA)
        const int ng = (gp + 1) & 7;
        rdAfrag((gp + 1) & 1, ng >> 2, ng & 3);
      }
      // stage one half-tile
      if (gp == 0)       stA(1, 0, t1);
      else if (gp == 1)  stA(1, 1, t1);
      else if (gp == 2)  stB(0, 0, t2);
      else if (gp == 3)  stB(0, 1, t2);
      else if (gp == 4)  stA(0, 0, t2);
      else if (gp == 5)  stA(0, 1, t2);
      else if (gp == 6)  stB(1, 0, t3);
      else               stB(1, 1, t3);
      WAITL(4);          // retire prev phase's reads (this phase's operands)
      SCHEDB;
      mfma16(gp & 1, gp & 3);
      // post-MFMA: bfr refills + repositioned vmcnt waits (still pre-barrier)
      if (gp == 2)      { WAITV(2); }            // A(t1)+B(t1) landed; slack +1 MFMA
      else if (gp == 3) { rdBfrag(1); SCHEDB; }
      else if (gp == 6) { WAITV(2); }            // tile t2 landed
      else if (gp == 7) { rdBfrag(0); SCHEDB; }
    }
  }
  // ---- peeled last iteration ----
  {
    const int t1 = 2 * (NIT - 1) + 1;
#pragma unroll
    for (int gp = 0; gp < 8; ++gp) {
      __builtin_amdgcn_s_barrier();
      SCHEDB;
      if (gp < 7) { const int ng = gp + 1; rdAfrag((gp + 1) & 1, ng >> 2, ng & 3); }
      if (gp == 0)       stA(1, 0, t1);
      else if (gp == 1)  stA(1, 1, t1);
      if (gp == 7) { WAITL(0); } else { WAITL(4); }
      SCHEDB;
      mfma16(gp & 1, gp & 3);
      if (gp == 2) { WAITV(0); }                 // tail drain: t1 landed
      else if (gp == 3) { rdBfrag(1); SCHEDB; }
    }
  }

  if constexpr (MODE == 1) {
#pragma unroll
    for (int mi = 0; mi < 8; mi++) {
      const int mrow = m0 + wr * 128 + mi * 16 + l4 * 4;
#pragma unroll
      for (int nj = 0; nj < 4; nj++) {
        const int col = n0 + wc * 64 + nj * 16 + l16;
        const float bi = bias[col];
#pragma unroll
        for (int jj = 0; jj < 4; jj++)
          outp[(size_t)(mrow + jj) * Ndim + col] = acc[mi][nj][jj] + bi;
      }
    }
  } else {
#pragma unroll
    for (int mi = 0; mi < 8; mi++) {
      const int mrow = m0 + wr * 128 + mi * 16 + l4 * 4;
      const int b = mrow >> 11, t0 = mrow & 2047;
#pragma unroll
      for (int nj = 0; nj < 4; nj++) {
        const int n = n0 + wc * 64 + nj * 16 + l16;
        const float bi = bias[n];
        const int part = n >> 11;          // 0=q 1=k 2=v
        const int hcol = n & 2047;
        const int h = hcol >> 7, d = hcol & 127;
        const int dm = d & 63;
        if (part == 2) {
          // V direct-transposed: vt[bh][d][t0..t0+3], one 8B store
          ushort4 vv;
          vv.x = f2bf(acc[mi][nj][0] + bi);
          vv.y = f2bf(acc[mi][nj][1] + bi);
          vv.z = f2bf(acc[mi][nj][2] + bi);
          vv.w = f2bf(acc[mi][nj][3] + bi);
          *(ushort4*)(vt + (((size_t)(b * NHn + h)) * HDn + d) * Tt + t0) = vv;
        } else {
#pragma unroll
          for (int jj = 0; jj < 4; jj++) {
            const int t = t0 + jj;
            float val = acc[mi][nj][jj] + bi;
            size_t didx = (((size_t)b * NHn + h) * Tt + t) * HDn + d;
            float partner = __shfl_xor(val, 1);
            float rh = (d & 1) ? partner : -partner;
            float cs = ctab[t * 64 + dm], sn = stab[t * 64 + dm];
            float o = val * cs + rh * sn;
            if (part == 0) q_r[didx] = f2bf(o * QSCALE);
            else           k_r[didx] = f2bf(o);
          }
        }
      }
    }
  }
}

// ---------------- flash attention (causal), overlapped LDS staging -------
// (unchanged from R4/R9 config)
__global__ __launch_bounds__(256, 2) void k_attn(
    const u16* __restrict__ q_r, const u16* __restrict__ k_r,
    const u16* __restrict__ vt, u16* __restrict__ y) {
  __shared__ u16 Ks[2][64 * 128];  // [buf][key][d], swizzled, 32KB
  __shared__ u16 Vs[128 * 64];     // V^T [d][key], swizzled, 16KB
  __shared__ u16 Ps[4][32 * 72];   // per-wave P, padded stride 144B, 18KB
  const int lin = blockIdx.x;           // 0..511
  const int swz = (lin & 7) * 64 + (lin >> 3);
  const int qpair = swz & 7;            // 0..7
  const int bh = swz >> 3;              // 0..63
  const int tid = threadIdx.x, w = tid >> 6, lane = tid & 63;
  const int l16 = lane & 15, l4 = lane >> 4;
  const int b = bh >> 4, h = bh & 15;

  const u16* kbase = k_r + (size_t)bh * Tt * HDn;
  const u16* vbase = vt + (size_t)bh * HDn * Tt;
  const f32x4 zf = {0.f, 0.f, 0.f, 0.f};

  auto stageK = [&](int buf, int j) {
    const char* ksrc = (const char*)(kbase + (size_t)j * 64 * HDn);
#pragma unroll
    for (int i = 0; i < 4; i++) {
      int op = tid * 16 + i * 4096;
      int ol = op ^ (((op >> 8) & 7) << 4);   // K rows are 256B
      gl_lds16(ksrc + ol, (char*)&Ks[buf][0] + op);
    }
  };
  auto stageV = [&](int j) {
    const char* vsrc = (const char*)(vbase + (size_t)j * 64);
#pragma unroll
    for (int i = 0; i < 4; i++) {
      int op = tid * 16 + i * 4096;
      int ol = op ^ (((op >> 7) & 7) << 4);   // V^T rows are 128B
      int row = ol >> 7, colb = ol & 127;
      gl_lds16(vsrc + (size_t)row * (Tt * 2) + colb, (char*)Vs + op);
    }
  };

#pragma unroll
  for (int qsel = 0; qsel < 2; ++qsel) {
    const int qt = qsel ? (15 - qpair) : qpair;

    const u16* qbase = q_r + ((size_t)bh * Tt + qt * 128 + w * 32) * HDn;
    bf16x8 qf[2][4];
#pragma unroll
    for (int mi = 0; mi < 2; mi++)
#pragma unroll
      for (int kc = 0; kc < 4; kc++)
        qf[mi][kc] = *(const bf16x8*)(qbase + (size_t)(mi * 16 + l16) * HDn + kc * 32 + l4 * 8);

    f32x4 acc_o[2][8];
#pragma unroll
    for (int mi = 0; mi < 2; mi++)
#pragma unroll
      for (int nf = 0; nf < 8; nf++) acc_o[mi][nf] = zf;
    float mrow[2][4], lrow[2][4];
#pragma unroll
    for (int mi = 0; mi < 2; mi++)
#pragma unroll
      for (int jj = 0; jj < 4; jj++) { mrow[mi][jj] = -1e30f; lrow[mi][jj] = 0.f; }

    const int ntiles = 2 * qt + 2;
    stageK(0, 0);
    __syncthreads();                 // K(0) landed + visible
    int cur = 0;

    for (int j = 0; j < ntiles; ++j) {
      const bool more = (j + 1 < ntiles);
      stageV(j);                     // 4 loads, consumed after mid barrier
      if (more) stageK(cur ^ 1, j + 1);  // 4 loads, consumed next iteration

      // ---- S = Q K^T from Ks[cur] ----
      f32x4 s[2][4];
#pragma unroll
      for (int mi = 0; mi < 2; mi++)
#pragma unroll
        for (int nj = 0; nj < 4; nj++) s[mi][nj] = zf;
#pragma unroll
      for (int kc = 0; kc < 4; kc++) {
        bf16x8 kf[4];
#pragma unroll
        for (int nj = 0; nj < 4; nj++) {
          int row = nj * 16 + l16;
          kf[nj] = *(const bf16x8*)((const char*)&Ks[cur][0] + row * 256 +
                                    ((kc * 64 + l4 * 16) ^ ((row & 7) << 4)));
        }
        __builtin_amdgcn_s_setprio(1);
#pragma unroll
        for (int mi = 0; mi < 2; mi++)
#pragma unroll
          for (int nj = 0; nj < 4; nj++)
            s[mi][nj] = __builtin_amdgcn_mfma_f32_16x16x32_bf16(qf[mi][kc], kf[nj], s[mi][nj], 0, 0, 0);
        __builtin_amdgcn_s_setprio(0);
      }

      // ---- online softmax (wave-parallel; rescale only when max grows) ----
      const bool diag = (j >= 2 * qt);
#pragma unroll
      for (int mi = 0; mi < 2; mi++) {
#pragma unroll
        for (int jj = 0; jj < 4; jj++) {
          if (diag) {
            const int qrow = qt * 128 + w * 32 + mi * 16 + l4 * 4 + jj;
#pragma unroll
            for (int nj = 0; nj < 4; nj++) {
              const int key = j * 64 + nj * 16 + l16;
              if (key > qrow) s[mi][nj][jj] = -1e30f;
            }
          }
          float lm = fmaxf(fmaxf(s[mi][0][jj], s[mi][1][jj]), fmaxf(s[mi][2][jj], s[mi][3][jj]));
#pragma unroll
          for (int dd = 1; dd < 16; dd <<= 1) lm = fmaxf(lm, __shfl_xor(lm, dd));
          if (lm > mrow[mi][jj]) {
            const float sc = __expf(mrow[mi][jj] - lm);
            mrow[mi][jj] = lm;
            lrow[mi][jj] *= sc;
#pragma unroll
            for (int nf = 0; nf < 8; nf++) acc_o[mi][nf][jj] *= sc;
          }
          float ps = 0.f;
#pragma unroll
          for (int nj = 0; nj < 4; nj++) {
            float p = __expf(s[mi][nj][jj] - mrow[mi][jj]);
            s[mi][nj][jj] = p;
            ps += p;
          }
#pragma unroll
          for (int dd = 1; dd < 16; dd <<= 1) ps += __shfl_xor(ps, dd);
          lrow[mi][jj] += ps;
          const int prow = mi * 16 + l4 * 4 + jj;
#pragma unroll
          for (int nj = 0; nj < 4; nj++)
            Ps[w][prow * 72 + nj * 16 + l16] = f2bf(s[mi][nj][jj]);
        }
      }

      // ---- V(j) landed? (K(j+1)'s 4 loads may remain in flight) ----
      if (more) { WAITV(4); } else { WAITV(0); }
      __builtin_amdgcn_s_barrier();

      // ---- O += P V from Vs ----
#pragma unroll
      for (int kc = 0; kc < 2; kc++) {
        bf16x8 pf[2];
#pragma unroll
        for (int mi = 0; mi < 2; mi++)
          pf[mi] = *(const bf16x8*)((const char*)&Ps[w][0] + (mi * 16 + l16) * 144 + kc * 64 + l4 * 16);
        bf16x8 vf[8];
#pragma unroll
        for (int nf = 0; nf < 8; nf++) {
          int row = nf * 16 + l16;
          vf[nf] = *(const bf16x8*)((const char*)Vs + row * 128 +
                                    ((kc * 64 + l4 * 16) ^ ((row & 7) << 4)));
        }
        __builtin_amdgcn_s_setprio(1);
#pragma unroll
        for (int nf = 0; nf < 8; nf++)
#pragma unroll
          for (int mi = 0; mi < 2; mi++)
            acc_o[mi][nf] = __builtin_amdgcn_mfma_f32_16x16x32_bf16(pf[mi], vf[nf], acc_o[mi][nf], 0, 0, 0);
        __builtin_amdgcn_s_setprio(0);
      }
      __syncthreads();               // drains vmcnt(0): K(j+1) landed; reads done
      cur ^= 1;
    }

    // ---- epilogue for this q-tile ----
#pragma unroll
    for (int mi = 0; mi < 2; mi++) {
#pragma unroll
      for (int jj = 0; jj < 4; jj++) {
        const float rinv = 1.f / lrow[mi][jj];
        const int t = qt * 128 + w * 32 + mi * 16 + l4 * 4 + jj;
        u16* yrow = y + ((size_t)b * Tt + t) * Ccn + h * HDn;
#pragma unroll
        for (int nf = 0; nf < 8; nf++)
          yrow[nf * 16 + l16] = f2bf(acc_o[mi][nf][jj] * rinv);
      }
    }
    __syncthreads();                 // all epilogue reads done before next qsel stages
  }
}

// ---------------- launcher ----------------

extern "C" void kernel_launch(void* const* d_in, const int* in_sizes, int n_in,
                              void* d_out, int out_size, void* d_ws, size_t ws_size,
                              hipStream_t stream) {
  const float* x     = (const float*)d_in[0];
  const float* Wqkv  = (const float*)d_in[1];
  const float* bqkv  = (const float*)d_in[2];
  const float* Wproj = (const float*)d_in[3];
  const float* bproj = (const float*)d_in[4];
  float* out = (float*)d_out;
  char* ws = (char*)d_ws;

  size_t off = 0;
  auto alloc = [&](size_t bytes) -> char* {
    char* p = ws + off;
    off += (bytes + 255) & ~(size_t)255;
    return p;
  };
  float* ctab  = (float*)alloc((size_t)Tt * 64 * sizeof(float));
  float* stab  = (float*)alloc((size_t)Tt * 64 * sizeof(float));
  u16* xb      = (u16*)alloc((size_t)MM * Ccn * 2);
  u16* WqkvT   = (u16*)alloc((size_t)NQKV * Ccn * 2);
  u16* WprojT  = (u16*)alloc((size_t)Ccn * Ccn * 2);
  u16* q_rb    = (u16*)alloc((size_t)MM * Ccn * 2);
  u16* k_rb    = (u16*)alloc((size_t)MM * Ccn * 2);
  u16* vtb     = (u16*)alloc((size_t)MM * Ccn * 2);   // V^T, written by GEMM1
  u16* ybuf    = (u16*)alloc((size_t)MM * Ccn * 2);

  k_prep<<<dim3(5632), 256, 0, stream>>>(x, xb, Wqkv, WqkvT, Wproj, WprojT, ctab, stab);

  k_gemm256<0><<<dim3((MM / 256) * (NQKV / 256)), 512, 0, stream>>>(
      xb, WqkvT, NQKV, NQKV / 256, bqkv, q_rb, k_rb, vtb, ctab, stab, nullptr);

  k_attn<<<dim3(512), 256, 0, stream>>>(q_rb, k_rb, vtb, ybuf);

  k_gemm256<1><<<dim3((MM / 256) * (Ccn / 256)), 512, 0, stream>>>(
      ybuf, WprojT, Ccn, Ccn / 256, bproj, nullptr, nullptr, nullptr, nullptr, nullptr, out);
}

// Round 11
// 444.809 us; speedup vs baseline: 1.2649x; 1.0000x over previous
//
#include <hip/hip_runtime.h>
#include <hip/hip_bf16.h>
#include <stdint.h>

#define DEV __device__ __forceinline__
#define WAITV(n) asm volatile("s_waitcnt vmcnt(" #n ")" ::: "memory")
#define WAITL(n) asm volatile("s_waitcnt lgkmcnt(" #n ")" ::: "memory")
#define SCHEDB __builtin_amdgcn_sched_barrier(0)

typedef __attribute__((ext_vector_type(4))) float f32x4;
typedef __attribute__((ext_vector_type(8))) short bf16x8;
typedef unsigned short u16;

constexpr int Bb = 4, Tt = 2048, Ccn = 2048, NHn = 16, HDn = 128;
constexpr int MM = Bb * Tt;          // 8192
constexpr int NQKV = 3 * Ccn;        // 6144
constexpr int KD = 2048;             // K dim for BOTH GEMMs
constexpr size_t K2 = (size_t)KD * 2;  // row stride bytes
constexpr size_t HKB = 128 * K2;       // half-tile row block bytes
constexpr float QSCALE = 0.08838834764831845f;  // 1/sqrt(128)

DEV u16 f2bf(float f) {
  __hip_bfloat16 h = __float2bfloat16(f);
  return *reinterpret_cast<u16*>(&h);
}

DEV void gl_lds16(const void* g, void* l) {
  __builtin_amdgcn_global_load_lds(
      (const __attribute__((address_space(1))) void*)g,
      (__attribute__((address_space(3))) void*)l, 16, 0, 0);
}

// ---------------- merged prep kernel ----------------
__global__ void k_prep(const float* __restrict__ x, u16* __restrict__ xb,
                       const float* __restrict__ Wqkv, u16* __restrict__ WqkvT,
                       const float* __restrict__ Wproj, u16* __restrict__ WprojT,
                       float* __restrict__ ct, float* __restrict__ st) {
  __shared__ u16 tile[64][72];
  const int bid = blockIdx.x, tid = threadIdx.x;
  if (bid < 1024) {
    const int n4 = (MM * Ccn) >> 2;
    for (int idx = bid * 256 + tid; idx < n4; idx += 1024 * 256) {
      float4 v = ((const float4*)x)[idx];
      ushort4 o;
      o.x = f2bf(v.x); o.y = f2bf(v.y); o.z = f2bf(v.z); o.w = f2bf(v.w);
      ((ushort4*)xb)[idx] = o;
    }
  } else if (bid < 5120) {
    const float* in; u16* out; int NC, bx, by;
    if (bid < 4096) {
      int t = bid - 1024; in = Wqkv; out = WqkvT; NC = NQKV; bx = t % 96; by = t / 96;
    } else {
      int t = bid - 4096; in = Wproj; out = WprojT; NC = Ccn; bx = t & 31; by = t >> 5;
    }
    const int R = 2048;
    int tr = by * 64, tc = bx * 64;
    int r = tid >> 2, c = (tid & 3) * 16;
    const float* src = in + (size_t)(tr + r) * NC + tc + c;
#pragma unroll
    for (int i = 0; i < 16; i++) tile[r][c + i] = f2bf(src[i]);
    __syncthreads();
    u16* dst = out + (size_t)(tc + r) * R + tr + c;
#pragma unroll
    for (int i = 0; i < 16; i++) dst[i] = tile[c + i][r];
  } else {
    int idx = (bid - 5120) * 256 + tid;   // < 131072 = Tt*64
    int t = idx >> 6, j = idx & 63;
    float invf = expf(-(float)j * 0.14391157f);  // ln(10000)/64
    float a = (float)t * invf;
    ct[idx] = cosf(a);
    st[idx] = sinf(a);
  }
}

// ---------------- 256x256 8-phase GEMM, ks-split register pipeline -------
// R10 diagnosis: LDS read bursts (8-read bfr refill + 4-read af pre-read)
// pile up at gp3/gp7->gp4/gp0 and the next WAITL stalls ~500-700cy every 4
// phases. Fix: split each phase into two ks-halves:
//   {afk0(next); stage; W1; 8 MFMA ks0; [B0 refill]; afk1(next); W2;
//    8 MFMA ks1; [B1 refill]}
// Bursts halve; each bfr half gets a full 8-MFMA cluster of slack.
// lgkm FIFO ledger (in-order retirement, counts = ds_read instrs):
//   W1 = 8 @gp0/gp4, else 4.  W2 = 8 @gp3/gp7, 6 @gp0/gp4, else 4.
// Prologue issues afk0,B0,afk1,B1 -> loop-entry FIFO == steady post-gp7
// shape; gp0's W1(8) covers it. vmcnt cadence unchanged from R10.

template <int MODE>
__global__ __launch_bounds__(512, 2) void k_gemm256(
    const u16* __restrict__ A, const u16* __restrict__ Bt,
    int Ndim, int NBX,
    const float* __restrict__ bias,
    u16* __restrict__ q_r, u16* __restrict__ k_r, u16* __restrict__ vt,
    const float* __restrict__ ctab, const float* __restrict__ stab,
    float* __restrict__ outp) {
  __shared__ __align__(16) u16 SM[65536];   // 128KB: A 64KB | B 64KB
  const int tid = threadIdx.x;
  const int w = tid >> 6, lane = tid & 63;
  const int l16 = lane & 15, l4 = lane >> 4;
  const int wr = w >> 2, wc = w & 3;
  const int bid = blockIdx.x, nwg = gridDim.x;
  const int swz = (bid & 7) * (nwg >> 3) + (bid >> 3);   // XCD-aware
  const int by = swz / NBX, bx = swz % NBX;
  const int m0 = by * 256, n0 = bx * 256;
  constexpr int NT = KD >> 6;      // 32
  constexpr int NIT = NT >> 1;     // 16

  // ---- precomputed LDS read bases (lane-constant) ----
  const int Mx = (l16 & 7) << 4;
  const int b6 = Mx & 64;
  const int lane_lo = l16 * 128 + ((l4 * 16) ^ (Mx & 48));
  const char* const pA0 = (const char*)SM + wr * 16384 + lane_lo + b6;
  const char* const pA1 = (const char*)SM + wr * 16384 + lane_lo + (64 - b6);
  const char* const pB0 = (const char*)SM + 65536 + (wc >> 1) * 16384 + (wc & 1) * 8192 + lane_lo + b6;
  const char* const pB1 = (const char*)SM + 65536 + (wc >> 1) * 16384 + (wc & 1) * 8192 + lane_lo + (64 - b6);

  // ---- staging: uniform base + 32-bit lane offset ----
  uint32_t soff[2];
#pragma unroll
  for (int i = 0; i < 2; i++) {
    int op = i * 8192 + tid * 16;
    int ol = op ^ (((op >> 7) & 7) << 4);
    int row = ol >> 7, colb = ol & 127;
    soff[i] = (uint32_t)(row * (int)K2 + colb);
  }
  const char* const Ab = (const char*)A + (size_t)m0 * K2;
  const char* const Bbp = (const char*)Bt + (size_t)n0 * K2;
  char* const dstBase = (char*)SM;

  auto stA = [&](int buf, int half, int kt) {
#pragma unroll
    for (int i = 0; i < 2; i++)
      gl_lds16(Ab + (size_t)half * HKB + (size_t)kt * 128 + soff[i],
               dstBase + buf * 32768 + half * 16384 + i * 8192 + tid * 16);
  };
  auto stB = [&](int buf, int half, int kt) {
#pragma unroll
    for (int i = 0; i < 2; i++)
      gl_lds16(Bbp + (size_t)half * HKB + (size_t)kt * 128 + soff[i],
               dstBase + 65536 + buf * 32768 + half * 16384 + i * 8192 + tid * 16);
  };

  bf16x8 af[2][2][2];   // [parity][dm][ks]
  bf16x8 bfr[4][2];     // [nj][ks] single-buffered
  f32x4 acc[8][4];
  const f32x4 zf = {0.f, 0.f, 0.f, 0.f};
#pragma unroll
  for (int i = 0; i < 8; i++)
#pragma unroll
    for (int j = 0; j < 4; j++) acc[i][j] = zf;

  auto rdAhalf = [&](int par, int bufsel, int ph, int ks) {
    const char* base = ks ? pA1 : pA0;
#pragma unroll
    for (int dm = 0; dm < 2; dm++)
      af[par][dm][ks] = *(const bf16x8*)(base + bufsel * 32768 + (ph * 2 + dm) * 2048);
  };
  auto rdBhalf = [&](int bufsel, int ks) {
    const char* base = ks ? pB1 : pB0;
#pragma unroll
    for (int nj = 0; nj < 4; nj++)
      bfr[nj][ks] = *(const bf16x8*)(base + bufsel * 32768 + nj * 2048);
  };
  auto mfma8 = [&](int par, int ph, int ks) {
    __builtin_amdgcn_s_setprio(1);
#pragma unroll
    for (int dm = 0; dm < 2; dm++)
#pragma unroll
      for (int nj = 0; nj < 4; nj++)
        acc[ph * 2 + dm][nj] = __builtin_amdgcn_mfma_f32_16x16x32_bf16(
            af[par][dm][ks], bfr[nj][ks], acc[ph * 2 + dm][nj], 0, 0, 0);
    __builtin_amdgcn_s_setprio(0);
  };

  // ---- prologue: tile0 (A,B) + B(t1); lgkm preloads in steady shape ----
  stA(0, 0, 0); stA(0, 1, 0); stB(0, 0, 0); stB(0, 1, 0);
  stB(1, 0, 1); stB(1, 1, 1);
  WAITV(4);                       // tile0 landed; B(t1) in flight
  __builtin_amdgcn_s_barrier();
  SCHEDB;
  rdAhalf(0, 0, 0, 0);   // afk0(gp0)
  rdBhalf(0, 0);         // B0(buf0)
  rdAhalf(0, 0, 0, 1);   // afk1(gp0)
  rdBhalf(0, 1);         // B1(buf0)
  // FIFO: [afk0:2][B0:4][afk1:2][B1:4] == steady post-gp7 shape

  for (int I = 0; I < NIT - 1; ++I) {
    const int t1 = 2 * I + 1, t2 = 2 * I + 2, t3 = 2 * I + 3;
#pragma unroll
    for (int gp = 0; gp < 8; ++gp) {
      __builtin_amdgcn_s_barrier();
      SCHEDB;
      { const int ng = (gp + 1) & 7; rdAhalf((gp + 1) & 1, ng >> 2, ng & 3, 0); }
      if (gp == 0)       stA(1, 0, t1);
      else if (gp == 1)  stA(1, 1, t1);
      else if (gp == 2)  stB(0, 0, t2);
      else if (gp == 3)  stB(0, 1, t2);
      else if (gp == 4)  stA(0, 0, t2);
      else if (gp == 5)  stA(0, 1, t2);
      else if (gp == 6)  stB(1, 0, t3);
      else               stB(1, 1, t3);
      if (gp == 0 || gp == 4) { WAITL(8); } else { WAITL(4); }
      SCHEDB;
      mfma8(gp & 1, gp & 3, 0);
      if (gp == 3)      rdBhalf(1, 0);
      else if (gp == 7) rdBhalf(0, 0);
      { const int ng = (gp + 1) & 7; rdAhalf((gp + 1) & 1, ng >> 2, ng & 3, 1); }
      if (gp == 3 || gp == 7) { WAITL(8); }
      else if (gp == 0 || gp == 4) { WAITL(6); }
      else { WAITL(4); }
      SCHEDB;
      mfma8(gp & 1, gp & 3, 1);
      if (gp == 3)      { rdBhalf(1, 1); SCHEDB; }
      else if (gp == 7) { rdBhalf(0, 1); SCHEDB; }
      if (gp == 2 || gp == 6) { WAITV(2); }
    }
  }
  // ---- peeled last iteration (tiles 2*NIT-2 buf0, 2*NIT-1 buf1) ----
  {
    const int t1 = 2 * (NIT - 1) + 1;
#pragma unroll
    for (int gp = 0; gp < 8; ++gp) {
      __builtin_amdgcn_s_barrier();
      SCHEDB;
      if (gp < 7) { const int ng = gp + 1; rdAhalf((gp + 1) & 1, ng >> 2, ng & 3, 0); }
      if (gp == 0)       stA(1, 0, t1);
      else if (gp == 1)  stA(1, 1, t1);
      if (gp == 0 || gp == 4) { WAITL(8); }
      else if (gp == 7) { WAITL(2); }
      else { WAITL(4); }
      SCHEDB;
      mfma8(gp & 1, gp & 3, 0);
      if (gp == 3) rdBhalf(1, 0);
      if (gp < 7) { const int ng = gp + 1; rdAhalf((gp + 1) & 1, ng >> 2, ng & 3, 1); }
      if (gp == 3) { WAITL(8); }
      else if (gp == 0 || gp == 4) { WAITL(6); }
      else if (gp == 7) { WAITL(0); }
      else { WAITL(4); }
      SCHEDB;
      mfma8(gp & 1, gp & 3, 1);
      if (gp == 3) { rdBhalf(1, 1); SCHEDB; }
      if (gp == 2) { WAITV(0); }
    }
  }

  if constexpr (MODE == 1) {
#pragma unroll
    for (int mi = 0; mi < 8; mi++) {
      const int mrow = m0 + wr * 128 + mi * 16 + l4 * 4;
#pragma unroll
      for (int nj = 0; nj < 4; nj++) {
        const int col = n0 + wc * 64 + nj * 16 + l16;
        const float bi = bias[col];
#pragma unroll
        for (int jj = 0; jj < 4; jj++)
          outp[(size_t)(mrow + jj) * Ndim + col] = acc[mi][nj][jj] + bi;
      }
    }
  } else {
#pragma unroll
    for (int mi = 0; mi < 8; mi++) {
      const int mrow = m0 + wr * 128 + mi * 16 + l4 * 4;
      const int b = mrow >> 11, t0 = mrow & 2047;
#pragma unroll
      for (int nj = 0; nj < 4; nj++) {
        const int n = n0 + wc * 64 + nj * 16 + l16;
        const float bi = bias[n];
        const int part = n >> 11;          // 0=q 1=k 2=v
        const int hcol = n & 2047;
        const int h = hcol >> 7, d = hcol & 127;
        const int dm = d & 63;
        if (part == 2) {
          ushort4 vv;
          vv.x = f2bf(acc[mi][nj][0] + bi);
          vv.y = f2bf(acc[mi][nj][1] + bi);
          vv.z = f2bf(acc[mi][nj][2] + bi);
          vv.w = f2bf(acc[mi][nj][3] + bi);
          *(ushort4*)(vt + (((size_t)(b * NHn + h)) * HDn + d) * Tt + t0) = vv;
        } else {
#pragma unroll
          for (int jj = 0; jj < 4; jj++) {
            const int t = t0 + jj;
            float val = acc[mi][nj][jj] + bi;
            size_t didx = (((size_t)b * NHn + h) * Tt + t) * HDn + d;
            float partner = __shfl_xor(val, 1);
            float rh = (d & 1) ? partner : -partner;
            float cs = ctab[t * 64 + dm], sn = stab[t * 64 + dm];
            float o = val * cs + rh * sn;
            if (part == 0) q_r[didx] = f2bf(o * QSCALE);
            else           k_r[didx] = f2bf(o);
          }
        }
      }
    }
  }
}

// ---------------- flash attention (causal), overlapped LDS staging -------
// (unchanged from R10 config)
__global__ __launch_bounds__(256, 2) void k_attn(
    const u16* __restrict__ q_r, const u16* __restrict__ k_r,
    const u16* __restrict__ vt, u16* __restrict__ y) {
  __shared__ u16 Ks[2][64 * 128];  // [buf][key][d], swizzled, 32KB
  __shared__ u16 Vs[128 * 64];     // V^T [d][key], swizzled, 16KB
  __shared__ u16 Ps[4][32 * 72];   // per-wave P, padded stride 144B, 18KB
  const int lin = blockIdx.x;           // 0..511
  const int swz = (lin & 7) * 64 + (lin >> 3);
  const int qpair = swz & 7;            // 0..7
  const int bh = swz >> 3;              // 0..63
  const int tid = threadIdx.x, w = tid >> 6, lane = tid & 63;
  const int l16 = lane & 15, l4 = lane >> 4;
  const int b = bh >> 4, h = bh & 15;

  const u16* kbase = k_r + (size_t)bh * Tt * HDn;
  const u16* vbase = vt + (size_t)bh * HDn * Tt;
  const f32x4 zf = {0.f, 0.f, 0.f, 0.f};

  auto stageK = [&](int buf, int j) {
    const char* ksrc = (const char*)(kbase + (size_t)j * 64 * HDn);
#pragma unroll
    for (int i = 0; i < 4; i++) {
      int op = tid * 16 + i * 4096;
      int ol = op ^ (((op >> 8) & 7) << 4);   // K rows are 256B
      gl_lds16(ksrc + ol, (char*)&Ks[buf][0] + op);
    }
  };
  auto stageV = [&](int j) {
    const char* vsrc = (const char*)(vbase + (size_t)j * 64);
#pragma unroll
    for (int i = 0; i < 4; i++) {
      int op = tid * 16 + i * 4096;
      int ol = op ^ (((op >> 7) & 7) << 4);   // V^T rows are 128B
      int row = ol >> 7, colb = ol & 127;
      gl_lds16(vsrc + (size_t)row * (Tt * 2) + colb, (char*)Vs + op);
    }
  };

#pragma unroll
  for (int qsel = 0; qsel < 2; ++qsel) {
    const int qt = qsel ? (15 - qpair) : qpair;

    const u16* qbase = q_r + ((size_t)bh * Tt + qt * 128 + w * 32) * HDn;
    bf16x8 qf[2][4];
#pragma unroll
    for (int mi = 0; mi < 2; mi++)
#pragma unroll
      for (int kc = 0; kc < 4; kc++)
        qf[mi][kc] = *(const bf16x8*)(qbase + (size_t)(mi * 16 + l16) * HDn + kc * 32 + l4 * 8);

    f32x4 acc_o[2][8];
#pragma unroll
    for (int mi = 0; mi < 2; mi++)
#pragma unroll
      for (int nf = 0; nf < 8; nf++) acc_o[mi][nf] = zf;
    float mrow[2][4], lrow[2][4];
#pragma unroll
    for (int mi = 0; mi < 2; mi++)
#pragma unroll
      for (int jj = 0; jj < 4; jj++) { mrow[mi][jj] = -1e30f; lrow[mi][jj] = 0.f; }

    const int ntiles = 2 * qt + 2;
    stageK(0, 0);
    __syncthreads();                 // K(0) landed + visible
    int cur = 0;

    for (int j = 0; j < ntiles; ++j) {
      const bool more = (j + 1 < ntiles);
      stageV(j);                     // 4 loads, consumed after mid barrier
      if (more) stageK(cur ^ 1, j + 1);  // 4 loads, consumed next iteration

      // ---- S = Q K^T from Ks[cur] ----
      f32x4 s[2][4];
#pragma unroll
      for (int mi = 0; mi < 2; mi++)
#pragma unroll
        for (int nj = 0; nj < 4; nj++) s[mi][nj] = zf;
#pragma unroll
      for (int kc = 0; kc < 4; kc++) {
        bf16x8 kf[4];
#pragma unroll
        for (int nj = 0; nj < 4; nj++) {
          int row = nj * 16 + l16;
          kf[nj] = *(const bf16x8*)((const char*)&Ks[cur][0] + row * 256 +
                                    ((kc * 64 + l4 * 16) ^ ((row & 7) << 4)));
        }
        __builtin_amdgcn_s_setprio(1);
#pragma unroll
        for (int mi = 0; mi < 2; mi++)
#pragma unroll
          for (int nj = 0; nj < 4; nj++)
            s[mi][nj] = __builtin_amdgcn_mfma_f32_16x16x32_bf16(qf[mi][kc], kf[nj], s[mi][nj], 0, 0, 0);
        __builtin_amdgcn_s_setprio(0);
      }

      // ---- online softmax (wave-parallel; rescale only when max grows) ----
      const bool diag = (j >= 2 * qt);
#pragma unroll
      for (int mi = 0; mi < 2; mi++) {
#pragma unroll
        for (int jj = 0; jj < 4; jj++) {
          if (diag) {
            const int qrow = qt * 128 + w * 32 + mi * 16 + l4 * 4 + jj;
#pragma unroll
            for (int nj = 0; nj < 4; nj++) {
              const int key = j * 64 + nj * 16 + l16;
              if (key > qrow) s[mi][nj][jj] = -1e30f;
            }
          }
          float lm = fmaxf(fmaxf(s[mi][0][jj], s[mi][1][jj]), fmaxf(s[mi][2][jj], s[mi][3][jj]));
#pragma unroll
          for (int dd = 1; dd < 16; dd <<= 1) lm = fmaxf(lm, __shfl_xor(lm, dd));
          if (lm > mrow[mi][jj]) {
            const float sc = __expf(mrow[mi][jj] - lm);
            mrow[mi][jj] = lm;
            lrow[mi][jj] *= sc;
#pragma unroll
            for (int nf = 0; nf < 8; nf++) acc_o[mi][nf][jj] *= sc;
          }
          float ps = 0.f;
#pragma unroll
          for (int nj = 0; nj < 4; nj++) {
            float p = __expf(s[mi][nj][jj] - mrow[mi][jj]);
            s[mi][nj][jj] = p;
            ps += p;
          }
#pragma unroll
          for (int dd = 1; dd < 16; dd <<= 1) ps += __shfl_xor(ps, dd);
          lrow[mi][jj] += ps;
          const int prow = mi * 16 + l4 * 4 + jj;
#pragma unroll
          for (int nj = 0; nj < 4; nj++)
            Ps[w][prow * 72 + nj * 16 + l16] = f2bf(s[mi][nj][jj]);
        }
      }

      // ---- V(j) landed? (K(j+1)'s 4 loads may remain in flight) ----
      if (more) { WAITV(4); } else { WAITV(0); }
      __builtin_amdgcn_s_barrier();

      // ---- O += P V from Vs ----
#pragma unroll
      for (int kc = 0; kc < 2; kc++) {
        bf16x8 pf[2];
#pragma unroll
        for (int mi = 0; mi < 2; mi++)
          pf[mi] = *(const bf16x8*)((const char*)&Ps[w][0] + (mi * 16 + l16) * 144 + kc * 64 + l4 * 16);
        bf16x8 vf[8];
#pragma unroll
        for (int nf = 0; nf < 8; nf++) {
          int row = nf * 16 + l16;
          vf[nf] = *(const bf16x8*)((const char*)Vs + row * 128 +
                                    ((kc * 64 + l4 * 16) ^ ((row & 7) << 4)));
        }
        __builtin_amdgcn_s_setprio(1);
#pragma unroll
        for (int nf = 0; nf < 8; nf++)
#pragma unroll
          for (int mi = 0; mi < 2; mi++)
            acc_o[mi][nf] = __builtin_amdgcn_mfma_f32_16x16x32_bf16(pf[mi], vf[nf], acc_o[mi][nf], 0, 0, 0);
        __builtin_amdgcn_s_setprio(0);
      }
      __syncthreads();               // drains vmcnt(0): K(j+1) landed; reads done
      cur ^= 1;
    }

    // ---- epilogue for this q-tile ----
#pragma unroll
    for (int mi = 0; mi < 2; mi++) {
#pragma unroll
      for (int jj = 0; jj < 4; jj++) {
        const float rinv = 1.f / lrow[mi][jj];
        const int t = qt * 128 + w * 32 + mi * 16 + l4 * 4 + jj;
        u16* yrow = y + ((size_t)b * Tt + t) * Ccn + h * HDn;
#pragma unroll
        for (int nf = 0; nf < 8; nf++)
          yrow[nf * 16 + l16] = f2bf(acc_o[mi][nf][jj] * rinv);
      }
    }
    __syncthreads();                 // all epilogue reads done before next qsel stages
  }
}

// ---------------- launcher ----------------

extern "C" void kernel_launch(void* const* d_in, const int* in_sizes, int n_in,
                              void* d_out, int out_size, void* d_ws, size_t ws_size,
                              hipStream_t stream) {
  const float* x     = (const float*)d_in[0];
  const float* Wqkv  = (const float*)d_in[1];
  const float* bqkv  = (const float*)d_in[2];
  const float* Wproj = (const float*)d_in[3];
  const float* bproj = (const float*)d_in[4];
  float* out = (float*)d_out;
  char* ws = (char*)d_ws;

  size_t off = 0;
  auto alloc = [&](size_t bytes) -> char* {
    char* p = ws + off;
    off += (bytes + 255) & ~(size_t)255;
    return p;
  };
  float* ctab  = (float*)alloc((size_t)Tt * 64 * sizeof(float));
  float* stab  = (float*)alloc((size_t)Tt * 64 * sizeof(float));
  u16* xb      = (u16*)alloc((size_t)MM * Ccn * 2);
  u16* WqkvT   = (u16*)alloc((size_t)NQKV * Ccn * 2);
  u16* WprojT  = (u16*)alloc((size_t)Ccn * Ccn * 2);
  u16* q_rb    = (u16*)alloc((size_t)MM * Ccn * 2);
  u16* k_rb    = (u16*)alloc((size_t)MM * Ccn * 2);
  u16* vtb     = (u16*)alloc((size_t)MM * Ccn * 2);   // V^T, written by GEMM1
  u16* ybuf    = (u16*)alloc((size_t)MM * Ccn * 2);

  k_prep<<<dim3(5632), 256, 0, stream>>>(x, xb, Wqkv, WqkvT, Wproj, WprojT, ctab, stab);

  k_gemm256<0><<<dim3((MM / 256) * (NQKV / 256)), 512, 0, stream>>>(
      xb, WqkvT, NQKV, NQKV / 256, bqkv, q_rb, k_rb, vtb, ctab, stab, nullptr);

  k_attn<<<dim3(512), 256, 0, stream>>>(q_rb, k_rb, vtb, ybuf);

  k_gemm256<1><<<dim3((MM / 256) * (Ccn / 256)), 512, 0, stream>>>(
      ybuf, WprojT, Ccn, Ccn / 256, bproj, nullptr, nullptr, nullptr, nullptr, nullptr, out);
}